// Round 1
// baseline (808.048 us; speedup 1.0000x reference)
//
#include <hip/hip_runtime.h>

#define DECAY 0.99f
#define ONE_MINUS_DECAY 0.01f
#define EPS 1e-5f

#define NROW 131072
#define DIM 64
#define NJ 512
#define RB 64     // rows per block
#define JT 128    // j-tile width

// d_out offsets (floats), in reference return order
#define OFF_Q    0          // quantize_st: 32*64*64*64 = 8388608
#define OFF_DIFF 8388608    // diff scalar
#define OFF_IND  8388609    // embed_ind: 131072
#define OFF_NE   8519681    // new_embed: 64*512
#define OFF_NCS  8552449    // new_cluster_size: 512
#define OFF_NEA  8552961    // new_embed_avg: 64*512

// ws offsets (floats)
#define WS_QNORM 0          // 512
#define WS_EMBT  512        // embed^T: 512*64
#define WS_ESUM  33280      // embed_sum^T: 512*64 (code-major)
#define WS_CNT   66048      // 512
#define WS_DIFF  66560      // 1
#define WS_N     66561      // 1
#define WS_TOTAL 66562

// kernel0: embed^T (code-major rows, contiguous 64f per code) + column norms
__global__ void k0_prep(const float* __restrict__ embed, float* __restrict__ ws) {
    int j = blockIdx.x * 256 + threadIdx.x;
    if (j < NJ) {
        float q = 0.f;
        #pragma unroll
        for (int d = 0; d < DIM; ++d) {
            float v = embed[d * NJ + j];
            q += v * v;
            ws[WS_EMBT + j * DIM + d] = v;
        }
        ws[WS_QNORM + j] = q;
    }
}

// kernel1: per 64-row block: distances, argmin, quantize, diff partial, atomic segment sums
__global__ __launch_bounds__(256) void k1_main(
        const float* __restrict__ x,
        const float* __restrict__ embed,
        float* __restrict__ ws,
        float* __restrict__ out) {
    __shared__ float X[DIM][RB + 1];   // transposed x tile, pad -> conflict-free
    __shared__ float E[DIM][JT];       // embed tile [d][j]
    __shared__ float qn[NJ];
    __shared__ float xn[RB];
    __shared__ float bval[RB];
    __shared__ int   bidx[RB];

    const int t = threadIdx.x;
    const int row0 = blockIdx.x * RB;

    // load X tile (coalesced read, 2-way-free transposed LDS write)
    #pragma unroll
    for (int k = 0; k < 4; ++k) {
        int f = t + 256 * k;
        int r = f >> 4, c4 = f & 15;
        float4 v = *(const float4*)(x + (size_t)(row0 + r) * DIM + 4 * c4);
        X[4*c4 + 0][r] = v.x;
        X[4*c4 + 1][r] = v.y;
        X[4*c4 + 2][r] = v.z;
        X[4*c4 + 3][r] = v.w;
    }
    if (t < 128) {
        *(float4*)&qn[4 * t] = *(const float4*)(ws + WS_QNORM + 4 * t);
    }
    __syncthreads();
    if (t < RB) {
        float s = 0.f;
        #pragma unroll
        for (int d = 0; d < DIM; ++d) { float v = X[d][t]; s += v * v; }
        xn[t] = s;
    }

    const int tx = t & 15, ty = t >> 4;   // 16 col-groups x 16 row-groups
    float best[4];
    int   besti[4];
    #pragma unroll
    for (int r = 0; r < 4; ++r) { best[r] = 3.4e38f; besti[r] = 0; }

    for (int jt = 0; jt < NJ / JT; ++jt) {
        __syncthreads();   // prev compute done (and xn visible on first iter)
        #pragma unroll
        for (int k = 0; k < 8; ++k) {
            int f = t + 256 * k;
            int d = f >> 5, c4 = f & 31;
            *(float4*)&E[d][4 * c4] =
                *(const float4*)(embed + (size_t)d * NJ + jt * JT + 4 * c4);
        }
        __syncthreads();

        float acc[4][8];
        #pragma unroll
        for (int r = 0; r < 4; ++r)
            #pragma unroll
            for (int c = 0; c < 8; ++c) acc[r][c] = 0.f;

        #pragma unroll 4
        for (int d = 0; d < DIM; ++d) {
            float4 xv = *(float4*)&X[d][4 * ty];
            float4 e0 = *(float4*)&E[d][8 * tx];
            float4 e1 = *(float4*)&E[d][8 * tx + 4];
            float xs[4] = {xv.x, xv.y, xv.z, xv.w};
            float es[8] = {e0.x, e0.y, e0.z, e0.w, e1.x, e1.y, e1.z, e1.w};
            #pragma unroll
            for (int r = 0; r < 4; ++r)
                #pragma unroll
                for (int c = 0; c < 8; ++c)
                    acc[r][c] = fmaf(xs[r], es[c], acc[r][c]);
        }

        // d = (||x||^2 - 2 s) + ||e||^2, running argmin (lowest index on ties)
        #pragma unroll
        for (int r = 0; r < 4; ++r) {
            float xnr = xn[4 * ty + r];
            #pragma unroll
            for (int c = 0; c < 8; ++c) {
                int j = jt * JT + 8 * tx + c;
                float dv = (xnr - 2.f * acc[r][c]) + qn[j];
                if (dv < best[r]) { best[r] = dv; besti[r] = j; }
            }
        }
    }

    // reduce argmin across the 16 tx lanes sharing each row
    #pragma unroll
    for (int r = 0; r < 4; ++r) {
        float bv = best[r];
        int   bi = besti[r];
        #pragma unroll
        for (int off = 1; off < 16; off <<= 1) {
            float ov = __shfl_xor(bv, off);
            int   oi = __shfl_xor(bi, off);
            if (ov < bv || (ov == bv && oi < bi)) { bv = ov; bi = oi; }
        }
        if (tx == 0) { bval[4 * ty + r] = bv; bidx[4 * ty + r] = bi; }
    }
    __syncthreads();

    // quantize write (match reference rounding: x + (q - x)) + embed_sum atomics
    {
        int r = t >> 2, c = t & 3;
        int bi = bidx[r];
        const float* eT = ws + WS_EMBT + (size_t)bi * DIM;
        #pragma unroll
        for (int k = 0; k < 4; ++k) {
            int c4 = c + 4 * k;
            float4 q = *(const float4*)(eT + 4 * c4);
            float x0 = X[4*c4+0][r], x1 = X[4*c4+1][r], x2 = X[4*c4+2][r], x3 = X[4*c4+3][r];
            float4 o;
            o.x = x0 + (q.x - x0);
            o.y = x1 + (q.y - x1);
            o.z = x2 + (q.z - x2);
            o.w = x3 + (q.w - x3);
            *(float4*)(out + OFF_Q + (size_t)(row0 + r) * DIM + 4 * c4) = o;
        }
        float* esum = ws + WS_ESUM + (size_t)bi * DIM;
        #pragma unroll
        for (int k = 0; k < 16; ++k) {
            int d = 4 * k + c;
            atomicAdd(esum + d, X[d][r]);
        }
    }
    // indices, counts, diff partial
    if (t < RB) {
        int bi = bidx[t];
        out[OFF_IND + row0 + t] = (float)bi;
        atomicAdd(ws + WS_CNT + bi, 1.0f);
        float v = bval[t];   // min distance == ||x - e||^2
        #pragma unroll
        for (int off = 1; off < 64; off <<= 1) v += __shfl_xor(v, off);
        if (t == 0) atomicAdd(ws + WS_DIFF, v);
    }
}

// kernel2a: new_cluster_size + n
__global__ void k2a(const float* __restrict__ cluster_size,
                    float* __restrict__ ws, float* __restrict__ out) {
    __shared__ float part[8];
    int j = threadIdx.x;  // 512 threads
    float ncs = cluster_size[j] * DECAY + ONE_MINUS_DECAY * ws[WS_CNT + j];
    out[OFF_NCS + j] = ncs;
    float v = ncs;
    #pragma unroll
    for (int off = 1; off < 64; off <<= 1) v += __shfl_xor(v, off);
    if ((j & 63) == 0) part[j >> 6] = v;
    __syncthreads();
    if (j == 0) {
        float n = 0.f;
        #pragma unroll
        for (int w = 0; w < 8; ++w) n += part[w];
        ws[WS_N] = n;
    }
}

// kernel2b: new_embed_avg, new_embed, diff
__global__ void k2b(const float* __restrict__ embed_avg,
                    const float* __restrict__ ws,
                    float* __restrict__ out) {
    int i4 = blockIdx.x * 256 + threadIdx.x;  // 0..8191
    int base = i4 * 4;
    int d  = base >> 9;
    int j0 = base & 511;
    float n = ws[WS_N];
    float denom = n + (float)NJ * EPS;
    float4 avg = *(const float4*)(embed_avg + base);
    float a[4] = {avg.x, avg.y, avg.z, avg.w};
    float4 nea, ne;
    float* pa = &nea.x;
    float* pe = &ne.x;
    #pragma unroll
    for (int k = 0; k < 4; ++k) {
        int j = j0 + k;
        float es  = ws[WS_ESUM + (size_t)j * DIM + d];
        float na  = a[k] * DECAY + ONE_MINUS_DECAY * es;
        float ncs = out[OFF_NCS + j];
        float cs  = (ncs + EPS) / denom * n;
        pa[k] = na;
        pe[k] = na / cs;
    }
    *(float4*)(out + OFF_NEA + base) = nea;
    *(float4*)(out + OFF_NE  + base) = ne;
    if (i4 == 0) out[OFF_DIFF] = ws[WS_DIFF] * (1.0f / 8388608.0f);
}

extern "C" void kernel_launch(void* const* d_in, const int* in_sizes, int n_in,
                              void* d_out, int out_size, void* d_ws, size_t ws_size,
                              hipStream_t stream) {
    const float* x            = (const float*)d_in[0];
    const float* embed        = (const float*)d_in[1];
    const float* cluster_size = (const float*)d_in[2];
    const float* embed_avg    = (const float*)d_in[3];
    float* out = (float*)d_out;
    float* ws  = (float*)d_ws;

    hipMemsetAsync(ws, 0, WS_TOTAL * sizeof(float), stream);
    k0_prep<<<2, 256, 0, stream>>>(embed, ws);
    k1_main<<<NROW / RB, 256, 0, stream>>>(x, embed, ws, out);
    k2a<<<1, 512, 0, stream>>>(cluster_size, ws, out);
    k2b<<<32, 256, 0, stream>>>(embed_avg, ws, out);
}

// Round 2
// 710.416 us; speedup vs baseline: 1.1374x; 1.1374x over previous
//
#include <hip/hip_runtime.h>

#define DECAY 0.99f
#define ONE_MINUS_DECAY 0.01f
#define EPS 1e-5f

#define NROW 131072
#define DIM 64
#define NJ 512
#define RB 64     // rows per block (k1)
#define JT 128    // j-tile width (k1)

// d_out offsets (floats), in reference return order
#define OFF_Q    0          // quantize_st: 8388608
#define OFF_DIFF 8388608    // diff scalar
#define OFF_IND  8388609    // embed_ind: 131072
#define OFF_NE   8519681    // new_embed: 64*512
#define OFF_NCS  8552449    // new_cluster_size: 512
#define OFF_NEA  8552961    // new_embed_avg: 64*512

// ws offsets (floats)
#define WS_QNORM 0          // 512
#define WS_EMBT  512        // embed^T: 512*64
#define WS_ESUM  33280      // embed_sum^T: 512*64 (code-major)
#define WS_CNT   66048      // 512
#define WS_DIFF  66560      // 1
#define WS_N     66561      // 1
#define WS_DIFFP 66564      // 2048 per-block diff partials (16B aligned)
#define WS_IND   68612      // 131072 ints (16B aligned)

// kernel0: embed^T (code-major rows) + column norms
__global__ void k0_prep(const float* __restrict__ embed, float* __restrict__ ws) {
    int j = blockIdx.x * 256 + threadIdx.x;
    if (j < NJ) {
        float q = 0.f;
        #pragma unroll
        for (int d = 0; d < DIM; ++d) {
            float v = embed[d * NJ + j];
            q += v * v;
            ws[WS_EMBT + j * DIM + d] = v;
        }
        ws[WS_QNORM + j] = q;
    }
}

// kernel1: distances, argmin, quantize, ind, per-block diff partial. NO atomics.
__global__ __launch_bounds__(256) void k1_main(
        const float* __restrict__ x,
        const float* __restrict__ embed,
        float* __restrict__ ws,
        float* __restrict__ out) {
    __shared__ float X[DIM][RB + 1];
    __shared__ float E[DIM][JT];
    __shared__ float qn[NJ];
    __shared__ float xn[RB];
    __shared__ float bval[RB];
    __shared__ int   bidx[RB];

    const int t = threadIdx.x;
    const int row0 = blockIdx.x * RB;

    #pragma unroll
    for (int k = 0; k < 4; ++k) {
        int f = t + 256 * k;
        int r = f >> 4, c4 = f & 15;
        float4 v = *(const float4*)(x + (size_t)(row0 + r) * DIM + 4 * c4);
        X[4*c4 + 0][r] = v.x;
        X[4*c4 + 1][r] = v.y;
        X[4*c4 + 2][r] = v.z;
        X[4*c4 + 3][r] = v.w;
    }
    if (t < 128) {
        *(float4*)&qn[4 * t] = *(const float4*)(ws + WS_QNORM + 4 * t);
    }
    __syncthreads();
    if (t < RB) {
        float s = 0.f;
        #pragma unroll
        for (int d = 0; d < DIM; ++d) { float v = X[d][t]; s += v * v; }
        xn[t] = s;
    }

    const int tx = t & 15, ty = t >> 4;
    float best[4];
    int   besti[4];
    #pragma unroll
    for (int r = 0; r < 4; ++r) { best[r] = 3.4e38f; besti[r] = 0; }

    for (int jt = 0; jt < NJ / JT; ++jt) {
        __syncthreads();
        #pragma unroll
        for (int k = 0; k < 8; ++k) {
            int f = t + 256 * k;
            int d = f >> 5, c4 = f & 31;
            *(float4*)&E[d][4 * c4] =
                *(const float4*)(embed + (size_t)d * NJ + jt * JT + 4 * c4);
        }
        __syncthreads();

        float acc[4][8];
        #pragma unroll
        for (int r = 0; r < 4; ++r)
            #pragma unroll
            for (int c = 0; c < 8; ++c) acc[r][c] = 0.f;

        #pragma unroll 4
        for (int d = 0; d < DIM; ++d) {
            float4 xv = *(float4*)&X[d][4 * ty];
            float4 e0 = *(float4*)&E[d][8 * tx];
            float4 e1 = *(float4*)&E[d][8 * tx + 4];
            float xs[4] = {xv.x, xv.y, xv.z, xv.w};
            float es[8] = {e0.x, e0.y, e0.z, e0.w, e1.x, e1.y, e1.z, e1.w};
            #pragma unroll
            for (int r = 0; r < 4; ++r)
                #pragma unroll
                for (int c = 0; c < 8; ++c)
                    acc[r][c] = fmaf(xs[r], es[c], acc[r][c]);
        }

        #pragma unroll
        for (int r = 0; r < 4; ++r) {
            float xnr = xn[4 * ty + r];
            #pragma unroll
            for (int c = 0; c < 8; ++c) {
                int j = jt * JT + 8 * tx + c;
                float dv = (xnr - 2.f * acc[r][c]) + qn[j];
                if (dv < best[r]) { best[r] = dv; besti[r] = j; }
            }
        }
    }

    #pragma unroll
    for (int r = 0; r < 4; ++r) {
        float bv = best[r];
        int   bi = besti[r];
        #pragma unroll
        for (int off = 1; off < 16; off <<= 1) {
            float ov = __shfl_xor(bv, off);
            int   oi = __shfl_xor(bi, off);
            if (ov < bv || (ov == bv && oi < bi)) { bv = ov; bi = oi; }
        }
        if (tx == 0) { bval[4 * ty + r] = bv; bidx[4 * ty + r] = bi; }
    }
    __syncthreads();

    // quantize write (x + (q - x) to match reference rounding)
    {
        int r = t >> 2, c = t & 3;
        int bi = bidx[r];
        const float* eT = ws + WS_EMBT + (size_t)bi * DIM;
        #pragma unroll
        for (int k = 0; k < 4; ++k) {
            int c4 = c + 4 * k;
            float4 q = *(const float4*)(eT + 4 * c4);
            float x0 = X[4*c4+0][r], x1 = X[4*c4+1][r], x2 = X[4*c4+2][r], x3 = X[4*c4+3][r];
            float4 o;
            o.x = x0 + (q.x - x0);
            o.y = x1 + (q.y - x1);
            o.z = x2 + (q.z - x2);
            o.w = x3 + (q.w - x3);
            *(float4*)(out + OFF_Q + (size_t)(row0 + r) * DIM + 4 * c4) = o;
        }
    }
    // indices (float for output, int for aligned rescan) + per-block diff partial
    if (t < RB) {
        int bi = bidx[t];
        out[OFF_IND + row0 + t] = (float)bi;
        ((int*)ws)[WS_IND + row0 + t] = bi;
        float v = bval[t];
        #pragma unroll
        for (int off = 1; off < 64; off <<= 1) v += __shfl_xor(v, off);
        if (t == 0) ws[WS_DIFFP + blockIdx.x] = v;
    }
}

// k_seg: one block per code; scan indices, gather+sum matching rows. NO atomics.
__global__ __launch_bounds__(256) void k_seg(
        const float* __restrict__ x,
        float* __restrict__ ws) {
    __shared__ float wsum[4][DIM];
    __shared__ float wcnt[4];
    const int j = blockIdx.x;
    const int t = threadIdx.x;
    const int lane = t & 63, wid = t >> 6;
    const int* __restrict__ ind = (const int*)ws + WS_IND;

    float acc[DIM];
    #pragma unroll
    for (int d = 0; d < DIM; ++d) acc[d] = 0.f;
    int cnt = 0;

    for (int i = 0; i < NROW / 4 / 256; ++i) {      // 128 iters
        int r4 = i * 256 + t;
        int4 iv = *(const int4*)(ind + 4 * r4);
        int rows[4] = {4*r4, 4*r4+1, 4*r4+2, 4*r4+3};
        int js[4] = {iv.x, iv.y, iv.z, iv.w};
        #pragma unroll
        for (int k = 0; k < 4; ++k) {
            if (js[k] == j) {
                const float4* xr = (const float4*)(x + (size_t)rows[k] * DIM);
                #pragma unroll
                for (int q = 0; q < 16; ++q) {
                    float4 v = xr[q];
                    acc[4*q+0] += v.x;
                    acc[4*q+1] += v.y;
                    acc[4*q+2] += v.z;
                    acc[4*q+3] += v.w;
                }
                cnt++;
            }
        }
    }

    // wave-reduce each dim, then combine 4 waves
    #pragma unroll
    for (int d = 0; d < DIM; ++d) {
        float v = acc[d];
        #pragma unroll
        for (int off = 1; off < 64; off <<= 1) v += __shfl_xor(v, off);
        if (lane == 0) wsum[wid][d] = v;
    }
    {
        float c = (float)cnt;
        #pragma unroll
        for (int off = 1; off < 64; off <<= 1) c += __shfl_xor(c, off);
        if (lane == 0) wcnt[wid] = c;
    }
    __syncthreads();
    if (t < DIM) {
        float s = wsum[0][t] + wsum[1][t] + wsum[2][t] + wsum[3][t];
        ws[WS_ESUM + (size_t)j * DIM + t] = s;
        if (t == 0) ws[WS_CNT + j] = wcnt[0] + wcnt[1] + wcnt[2] + wcnt[3];
    }
}

// k2a: new_cluster_size, n, total diff
__global__ void k2a(const float* __restrict__ cluster_size,
                    float* __restrict__ ws, float* __restrict__ out) {
    __shared__ float part[8];
    __shared__ float dpart[8];
    int j = threadIdx.x;  // 512 threads
    float ncs = cluster_size[j] * DECAY + ONE_MINUS_DECAY * ws[WS_CNT + j];
    out[OFF_NCS + j] = ncs;
    float4 dp = *(const float4*)(ws + WS_DIFFP + 4 * j);
    float dv = dp.x + dp.y + dp.z + dp.w;
    float v = ncs;
    #pragma unroll
    for (int off = 1; off < 64; off <<= 1) {
        v  += __shfl_xor(v, off);
        dv += __shfl_xor(dv, off);
    }
    if ((j & 63) == 0) { part[j >> 6] = v; dpart[j >> 6] = dv; }
    __syncthreads();
    if (j == 0) {
        float n = 0.f, dt = 0.f;
        #pragma unroll
        for (int w = 0; w < 8; ++w) { n += part[w]; dt += dpart[w]; }
        ws[WS_N] = n;
        ws[WS_DIFF] = dt;
    }
}

// k2b: new_embed_avg, new_embed, diff
__global__ void k2b(const float* __restrict__ embed_avg,
                    const float* __restrict__ ws,
                    float* __restrict__ out) {
    int i4 = blockIdx.x * 256 + threadIdx.x;  // 0..8191
    int base = i4 * 4;
    int d  = base >> 9;
    int j0 = base & 511;
    float n = ws[WS_N];
    float denom = n + (float)NJ * EPS;
    float4 avg = *(const float4*)(embed_avg + base);
    float a[4] = {avg.x, avg.y, avg.z, avg.w};
    float4 nea, ne;
    float* pa = &nea.x;
    float* pe = &ne.x;
    #pragma unroll
    for (int k = 0; k < 4; ++k) {
        int j = j0 + k;
        float es  = ws[WS_ESUM + (size_t)j * DIM + d];
        float na  = a[k] * DECAY + ONE_MINUS_DECAY * es;
        float ncs = out[OFF_NCS + j];
        float cs  = (ncs + EPS) / denom * n;
        pa[k] = na;
        pe[k] = na / cs;
    }
    *(float4*)(out + OFF_NEA + base) = nea;
    *(float4*)(out + OFF_NE  + base) = ne;
    if (i4 == 0) out[OFF_DIFF] = ws[WS_DIFF] * (1.0f / 8388608.0f);
}

extern "C" void kernel_launch(void* const* d_in, const int* in_sizes, int n_in,
                              void* d_out, int out_size, void* d_ws, size_t ws_size,
                              hipStream_t stream) {
    const float* x            = (const float*)d_in[0];
    const float* embed        = (const float*)d_in[1];
    const float* cluster_size = (const float*)d_in[2];
    const float* embed_avg    = (const float*)d_in[3];
    float* out = (float*)d_out;
    float* ws  = (float*)d_ws;

    k0_prep<<<2, 256, 0, stream>>>(embed, ws);
    k1_main<<<NROW / RB, 256, 0, stream>>>(x, embed, ws, out);
    k_seg<<<NJ, 256, 0, stream>>>(x, ws);
    k2a<<<1, 512, 0, stream>>>(cluster_size, ws, out);
    k2b<<<32, 256, 0, stream>>>(embed_avg, ws, out);
}

// Round 5
// 408.385 us; speedup vs baseline: 1.9786x; 1.7396x over previous
//
#include <hip/hip_runtime.h>

#define DECAY 0.99f
#define ONE_MINUS_DECAY 0.01f
#define EPS 1e-5f

#define NROW 131072
#define DIM 64
#define NJ 512
#define RB 64     // rows per block (k1)
#define JT 128    // j-tile width (k1)

// d_out offsets (floats), in reference return order
#define OFF_Q    0          // quantize_st: 8388608
#define OFF_DIFF 8388608    // diff scalar
#define OFF_IND  8388609    // embed_ind: 131072
#define OFF_NE   8519681    // new_embed: 64*512
#define OFF_NCS  8552449    // new_cluster_size: 512
#define OFF_NEA  8552961    // new_embed_avg: 64*512

// ws offsets (floats)
#define WS_QNORM 0          // 512
#define WS_EMBT  512        // embed^T: 512*64
#define WS_ESUM  33280      // embed_sum^T: 512*64 (code-major)
#define WS_CNT   66048      // 512
#define WS_DIFF  66560      // 1
#define WS_N     66561      // 1
#define WS_DIFFP 66564      // 2048 per-block diff partials
#define WS_IND   68612      // 131072 ints
#define WS_PART  199684     // NACC * 33280 partials ([j][d] sums + counts)
#define PART_STRIDE 33280

// kernel0: embed^T (code-major rows) + column norms
__global__ void k0_prep(const float* __restrict__ embed, float* __restrict__ ws) {
    int j = blockIdx.x * 256 + threadIdx.x;
    if (j < NJ) {
        float q = 0.f;
        #pragma unroll
        for (int d = 0; d < DIM; ++d) {
            float v = embed[d * NJ + j];
            q += v * v;
            ws[WS_EMBT + j * DIM + d] = v;
        }
        ws[WS_QNORM + j] = q;
    }
}

// kernel1: distances, argmin, quantize, ind, per-block diff partial. NO atomics.
__global__ __launch_bounds__(256) void k1_main(
        const float* __restrict__ x,
        const float* __restrict__ embed,
        float* __restrict__ ws,
        float* __restrict__ out) {
    __shared__ float X[DIM][RB + 1];
    __shared__ float E[DIM][JT];
    __shared__ float qn[NJ];
    __shared__ float xn[RB];
    __shared__ float bval[RB];
    __shared__ int   bidx[RB];

    const int t = threadIdx.x;
    const int row0 = blockIdx.x * RB;

    #pragma unroll
    for (int k = 0; k < 4; ++k) {
        int f = t + 256 * k;
        int r = f >> 4, c4 = f & 15;
        float4 v = *(const float4*)(x + (size_t)(row0 + r) * DIM + 4 * c4);
        X[4*c4 + 0][r] = v.x;
        X[4*c4 + 1][r] = v.y;
        X[4*c4 + 2][r] = v.z;
        X[4*c4 + 3][r] = v.w;
    }
    if (t < 128) {
        *(float4*)&qn[4 * t] = *(const float4*)(ws + WS_QNORM + 4 * t);
    }
    __syncthreads();
    if (t < RB) {
        float s = 0.f;
        #pragma unroll
        for (int d = 0; d < DIM; ++d) { float v = X[d][t]; s += v * v; }
        xn[t] = s;
    }

    const int tx = t & 15, ty = t >> 4;
    float best[4];
    int   besti[4];
    #pragma unroll
    for (int r = 0; r < 4; ++r) { best[r] = 3.4e38f; besti[r] = 0; }

    for (int jt = 0; jt < NJ / JT; ++jt) {
        __syncthreads();
        #pragma unroll
        for (int k = 0; k < 8; ++k) {
            int f = t + 256 * k;
            int d = f >> 5, c4 = f & 31;
            *(float4*)&E[d][4 * c4] =
                *(const float4*)(embed + (size_t)d * NJ + jt * JT + 4 * c4);
        }
        __syncthreads();

        float acc[4][8];
        #pragma unroll
        for (int r = 0; r < 4; ++r)
            #pragma unroll
            for (int c = 0; c < 8; ++c) acc[r][c] = 0.f;

        #pragma unroll 4
        for (int d = 0; d < DIM; ++d) {
            float4 xv = *(float4*)&X[d][4 * ty];
            float4 e0 = *(float4*)&E[d][8 * tx];
            float4 e1 = *(float4*)&E[d][8 * tx + 4];
            float xs[4] = {xv.x, xv.y, xv.z, xv.w};
            float es[8] = {e0.x, e0.y, e0.z, e0.w, e1.x, e1.y, e1.z, e1.w};
            #pragma unroll
            for (int r = 0; r < 4; ++r)
                #pragma unroll
                for (int c = 0; c < 8; ++c)
                    acc[r][c] = fmaf(xs[r], es[c], acc[r][c]);
        }

        #pragma unroll
        for (int r = 0; r < 4; ++r) {
            float xnr = xn[4 * ty + r];
            #pragma unroll
            for (int c = 0; c < 8; ++c) {
                int j = jt * JT + 8 * tx + c;
                float dv = (xnr - 2.f * acc[r][c]) + qn[j];
                if (dv < best[r]) { best[r] = dv; besti[r] = j; }
            }
        }
    }

    #pragma unroll
    for (int r = 0; r < 4; ++r) {
        float bv = best[r];
        int   bi = besti[r];
        #pragma unroll
        for (int off = 1; off < 16; off <<= 1) {
            float ov = __shfl_xor(bv, off);
            int   oi = __shfl_xor(bi, off);
            if (ov < bv || (ov == bv && oi < bi)) { bv = ov; bi = oi; }
        }
        if (tx == 0) { bval[4 * ty + r] = bv; bidx[4 * ty + r] = bi; }
    }
    __syncthreads();

    {
        int r = t >> 2, c = t & 3;
        int bi = bidx[r];
        const float* eT = ws + WS_EMBT + (size_t)bi * DIM;
        #pragma unroll
        for (int k = 0; k < 4; ++k) {
            int c4 = c + 4 * k;
            float4 q = *(const float4*)(eT + 4 * c4);
            float x0 = X[4*c4+0][r], x1 = X[4*c4+1][r], x2 = X[4*c4+2][r], x3 = X[4*c4+3][r];
            float4 o;
            o.x = x0 + (q.x - x0);
            o.y = x1 + (q.y - x1);
            o.z = x2 + (q.z - x2);
            o.w = x3 + (q.w - x3);
            *(float4*)(out + OFF_Q + (size_t)(row0 + r) * DIM + 4 * c4) = o;
        }
    }
    if (t < RB) {
        int bi = bidx[t];
        out[OFF_IND + row0 + t] = (float)bi;
        ((int*)ws)[WS_IND + row0 + t] = bi;
        float v = bval[t];
        #pragma unroll
        for (int off = 1; off < 64; off <<= 1) v += __shfl_xor(v, off);
        if (t == 0) ws[WS_DIFFP + blockIdx.x] = v;
    }
}

// k_acc: LDS-histogram segment sum. NACC blocks x 1024 threads, 135 KB LDS.
// acc[j][65-pad] -> bank = (j + off) % 32: random-j atomics spread across banks.
__global__ __launch_bounds__(1024) void k_acc(
        const float* __restrict__ x,
        float* __restrict__ ws,
        int rows_per_blk) {
    __shared__ float acc[NJ * 65];
    __shared__ float cnt[NJ];
    const int t = threadIdx.x;
    for (int i = t; i < NJ * 65; i += 1024) acc[i] = 0.f;
    if (t < NJ) cnt[t] = 0.f;
    __syncthreads();

    const int* __restrict__ ind = (const int*)ws + WS_IND;
    const int row0 = blockIdx.x * rows_per_blk;
    const int fq = t & 15, rg = t >> 4;   // 64 row-groups x 16 float4-slots

    for (int r = rg; r < rows_per_blk; r += 64) {
        int row = row0 + r;
        int j = ind[row];
        float4 v = *(const float4*)(x + (size_t)row * DIM + 4 * fq);
        float* a = acc + j * 65 + 4 * fq;
        atomicAdd(a + 0, v.x);
        atomicAdd(a + 1, v.y);
        atomicAdd(a + 2, v.z);
        atomicAdd(a + 3, v.w);
        if (fq == 0) atomicAdd(&cnt[j], 1.f);
    }
    __syncthreads();

    float* part = ws + WS_PART + (size_t)blockIdx.x * PART_STRIDE;
    for (int i = t; i < NJ * DIM; i += 1024)
        part[i] = acc[(i >> 6) * 65 + (i & 63)];
    if (t < NJ) part[NJ * DIM + t] = cnt[t];
}

// k_red: sum NACC partials -> ESUM + CNT. 130 blocks x 256 (33280 outputs).
__global__ void k_red(float* __restrict__ ws, int nacc) {
    int o = blockIdx.x * 256 + threadIdx.x;
    if (o >= PART_STRIDE) return;
    float s = 0.f;
    for (int b = 0; b < nacc; ++b)
        s += ws[WS_PART + (size_t)b * PART_STRIDE + o];
    if (o < NJ * DIM) ws[WS_ESUM + o] = s;
    else              ws[WS_CNT + (o - NJ * DIM)] = s;
}

// fallback (tiny ws): scan-per-code segment sum (correct, slow)
__global__ __launch_bounds__(256) void k_seg(
        const float* __restrict__ x,
        float* __restrict__ ws) {
    __shared__ float wsum[4][DIM];
    __shared__ float wcnt[4];
    const int j = blockIdx.x;
    const int t = threadIdx.x;
    const int lane = t & 63, wid = t >> 6;
    const int* __restrict__ ind = (const int*)ws + WS_IND;

    float acc[DIM];
    #pragma unroll
    for (int d = 0; d < DIM; ++d) acc[d] = 0.f;
    int cnt = 0;

    for (int i = 0; i < NROW / 4 / 256; ++i) {
        int r4 = i * 256 + t;
        int4 iv = *(const int4*)(ind + 4 * r4);
        int rows[4] = {4*r4, 4*r4+1, 4*r4+2, 4*r4+3};
        int js[4] = {iv.x, iv.y, iv.z, iv.w};
        #pragma unroll
        for (int k = 0; k < 4; ++k) {
            if (js[k] == j) {
                const float4* xr = (const float4*)(x + (size_t)rows[k] * DIM);
                #pragma unroll
                for (int q = 0; q < 16; ++q) {
                    float4 v = xr[q];
                    acc[4*q+0] += v.x; acc[4*q+1] += v.y;
                    acc[4*q+2] += v.z; acc[4*q+3] += v.w;
                }
                cnt++;
            }
        }
    }
    #pragma unroll
    for (int d = 0; d < DIM; ++d) {
        float v = acc[d];
        #pragma unroll
        for (int off = 1; off < 64; off <<= 1) v += __shfl_xor(v, off);
        if (lane == 0) wsum[wid][d] = v;
    }
    {
        float c = (float)cnt;
        #pragma unroll
        for (int off = 1; off < 64; off <<= 1) c += __shfl_xor(c, off);
        if (lane == 0) wcnt[wid] = c;
    }
    __syncthreads();
    if (t < DIM) {
        float s = wsum[0][t] + wsum[1][t] + wsum[2][t] + wsum[3][t];
        ws[WS_ESUM + (size_t)j * DIM + t] = s;
        if (t == 0) ws[WS_CNT + j] = wcnt[0] + wcnt[1] + wcnt[2] + wcnt[3];
    }
}

// k2a: new_cluster_size, n, total diff
__global__ void k2a(const float* __restrict__ cluster_size,
                    float* __restrict__ ws, float* __restrict__ out) {
    __shared__ float part[8];
    __shared__ float dpart[8];
    int j = threadIdx.x;  // 512 threads
    float ncs = cluster_size[j] * DECAY + ONE_MINUS_DECAY * ws[WS_CNT + j];
    out[OFF_NCS + j] = ncs;
    float4 dp = *(const float4*)(ws + WS_DIFFP + 4 * j);
    float dv = dp.x + dp.y + dp.z + dp.w;
    float v = ncs;
    #pragma unroll
    for (int off = 1; off < 64; off <<= 1) {
        v  += __shfl_xor(v, off);
        dv += __shfl_xor(dv, off);
    }
    if ((j & 63) == 0) { part[j >> 6] = v; dpart[j >> 6] = dv; }
    __syncthreads();
    if (j == 0) {
        float n = 0.f, dt = 0.f;
        #pragma unroll
        for (int w = 0; w < 8; ++w) { n += part[w]; dt += dpart[w]; }
        ws[WS_N] = n;
        ws[WS_DIFF] = dt;
    }
}

// k2b: new_embed_avg, new_embed, diff
__global__ void k2b(const float* __restrict__ embed_avg,
                    const float* __restrict__ ws,
                    float* __restrict__ out) {
    int i4 = blockIdx.x * 256 + threadIdx.x;  // 0..8191
    int base = i4 * 4;
    int d  = base >> 9;
    int j0 = base & 511;
    float n = ws[WS_N];
    float denom = n + (float)NJ * EPS;
    float4 avg = *(const float4*)(embed_avg + base);
    float a[4] = {avg.x, avg.y, avg.z, avg.w};
    float4 nea, ne;
    float* pa = &nea.x;
    float* pe = &ne.x;
    #pragma unroll
    for (int k = 0; k < 4; ++k) {
        int j = j0 + k;
        float es  = ws[WS_ESUM + (size_t)j * DIM + d];
        float na  = a[k] * DECAY + ONE_MINUS_DECAY * es;
        float ncs = out[OFF_NCS + j];
        float cs  = (ncs + EPS) / denom * n;
        pa[k] = na;
        pe[k] = na / cs;
    }
    *(float4*)(out + OFF_NEA + base) = nea;
    *(float4*)(out + OFF_NE  + base) = ne;
    if (i4 == 0) out[OFF_DIFF] = ws[WS_DIFF] * (1.0f / 8388608.0f);
}

extern "C" void kernel_launch(void* const* d_in, const int* in_sizes, int n_in,
                              void* d_out, int out_size, void* d_ws, size_t ws_size,
                              hipStream_t stream) {
    const float* x            = (const float*)d_in[0];
    const float* embed        = (const float*)d_in[1];
    const float* cluster_size = (const float*)d_in[2];
    const float* embed_avg    = (const float*)d_in[3];
    float* out = (float*)d_out;
    float* ws  = (float*)d_ws;

    // pick NACC (power of 2, <=64) so partials fit in ws
    size_t ws_floats = ws_size / 4;
    size_t avail = ws_floats > WS_PART ? ws_floats - WS_PART : 0;
    int nacc = 64;
    while (nacc > 1 && (size_t)nacc * PART_STRIDE > avail) nacc >>= 1;
    bool use_acc = (size_t)nacc * PART_STRIDE <= avail;

    k0_prep<<<2, 256, 0, stream>>>(embed, ws);
    k1_main<<<NROW / RB, 256, 0, stream>>>(x, embed, ws, out);
    if (use_acc) {
        k_acc<<<nacc, 1024, 0, stream>>>(x, ws, NROW / nacc);
        k_red<<<(PART_STRIDE + 255) / 256, 256, 0, stream>>>(ws, nacc);
    } else {
        k_seg<<<NJ, 256, 0, stream>>>(x, ws);
    }
    k2a<<<1, 512, 0, stream>>>(cluster_size, ws, out);
    k2b<<<32, 256, 0, stream>>>(embed_avg, ws, out);
}

// Round 7
// 344.649 us; speedup vs baseline: 2.3446x; 1.1849x over previous
//
#include <hip/hip_runtime.h>

#define DECAY 0.99f
#define ONE_MINUS_DECAY 0.01f
#define EPS 1e-5f

#define NROW 131072
#define DIM 64
#define NJ 512
#define RB 64     // rows per block (k1)
#define JT 128    // j-tile width (k1)

// d_out offsets (floats), in reference return order
#define OFF_Q    0          // quantize_st: 8388608
#define OFF_DIFF 8388608    // diff scalar
#define OFF_IND  8388609    // embed_ind: 131072
#define OFF_NE   8519681    // new_embed: 64*512
#define OFF_NCS  8552449    // new_cluster_size: 512
#define OFF_NEA  8552961    // new_embed_avg: 64*512

// ws offsets (floats)
#define WS_QNORM 0          // 512
#define WS_EMBT  512        // embed^T: 512*64
#define WS_ESUM  33280      // embed_sum^T: 512*64 (code-major)
#define WS_CNT   66048      // 512
#define WS_DIFF  66560      // 1
#define WS_N     66561      // 1
#define WS_DIFFP 66564      // 2048 per-block diff partials
#define WS_IND   68612      // 131072 ints
#define WS_PART  199684     // nacc * 33280 partials ([j][d] sums + counts)
#define PART_STRIDE 33280

// kernel0: embed^T (code-major rows) + column norms
__global__ void k0_prep(const float* __restrict__ embed, float* __restrict__ ws) {
    int j = blockIdx.x * 256 + threadIdx.x;
    if (j < NJ) {
        float q = 0.f;
        #pragma unroll
        for (int d = 0; d < DIM; ++d) {
            float v = embed[d * NJ + j];
            q += v * v;
            ws[WS_EMBT + j * DIM + d] = v;
        }
        ws[WS_QNORM + j] = q;
    }
}

// kernel1: distances, argmin, quantize, ind, per-block diff partial. NO atomics.
__global__ __launch_bounds__(256) void k1_main(
        const float* __restrict__ x,
        const float* __restrict__ embed,
        float* __restrict__ ws,
        float* __restrict__ out) {
    __shared__ float X[DIM][RB + 1];
    __shared__ float E[DIM][JT];
    __shared__ float qn[NJ];
    __shared__ float xn[RB];
    __shared__ float bval[RB];
    __shared__ int   bidx[RB];

    const int t = threadIdx.x;
    const int row0 = blockIdx.x * RB;

    #pragma unroll
    for (int k = 0; k < 4; ++k) {
        int f = t + 256 * k;
        int r = f >> 4, c4 = f & 15;
        float4 v = *(const float4*)(x + (size_t)(row0 + r) * DIM + 4 * c4);
        X[4*c4 + 0][r] = v.x;
        X[4*c4 + 1][r] = v.y;
        X[4*c4 + 2][r] = v.z;
        X[4*c4 + 3][r] = v.w;
    }
    if (t < 128) {
        *(float4*)&qn[4 * t] = *(const float4*)(ws + WS_QNORM + 4 * t);
    }
    __syncthreads();
    if (t < RB) {
        float s = 0.f;
        #pragma unroll
        for (int d = 0; d < DIM; ++d) { float v = X[d][t]; s += v * v; }
        xn[t] = s;
    }

    const int tx = t & 15, ty = t >> 4;
    float best[4];
    int   besti[4];
    #pragma unroll
    for (int r = 0; r < 4; ++r) { best[r] = 3.4e38f; besti[r] = 0; }

    for (int jt = 0; jt < NJ / JT; ++jt) {
        __syncthreads();
        #pragma unroll
        for (int k = 0; k < 8; ++k) {
            int f = t + 256 * k;
            int d = f >> 5, c4 = f & 31;
            *(float4*)&E[d][4 * c4] =
                *(const float4*)(embed + (size_t)d * NJ + jt * JT + 4 * c4);
        }
        __syncthreads();

        float acc[4][8];
        #pragma unroll
        for (int r = 0; r < 4; ++r)
            #pragma unroll
            for (int c = 0; c < 8; ++c) acc[r][c] = 0.f;

        #pragma unroll 4
        for (int d = 0; d < DIM; ++d) {
            float4 xv = *(float4*)&X[d][4 * ty];
            float4 e0 = *(float4*)&E[d][8 * tx];
            float4 e1 = *(float4*)&E[d][8 * tx + 4];
            float xs[4] = {xv.x, xv.y, xv.z, xv.w};
            float es[8] = {e0.x, e0.y, e0.z, e0.w, e1.x, e1.y, e1.z, e1.w};
            #pragma unroll
            for (int r = 0; r < 4; ++r)
                #pragma unroll
                for (int c = 0; c < 8; ++c)
                    acc[r][c] = fmaf(xs[r], es[c], acc[r][c]);
        }

        #pragma unroll
        for (int r = 0; r < 4; ++r) {
            float xnr = xn[4 * ty + r];
            #pragma unroll
            for (int c = 0; c < 8; ++c) {
                int j = jt * JT + 8 * tx + c;
                float dv = (xnr - 2.f * acc[r][c]) + qn[j];
                if (dv < best[r]) { best[r] = dv; besti[r] = j; }
            }
        }
    }

    #pragma unroll
    for (int r = 0; r < 4; ++r) {
        float bv = best[r];
        int   bi = besti[r];
        #pragma unroll
        for (int off = 1; off < 16; off <<= 1) {
            float ov = __shfl_xor(bv, off);
            int   oi = __shfl_xor(bi, off);
            if (ov < bv || (ov == bv && oi < bi)) { bv = ov; bi = oi; }
        }
        if (tx == 0) { bval[4 * ty + r] = bv; bidx[4 * ty + r] = bi; }
    }
    __syncthreads();

    {
        int r = t >> 2, c = t & 3;
        int bi = bidx[r];
        const float* eT = ws + WS_EMBT + (size_t)bi * DIM;
        #pragma unroll
        for (int k = 0; k < 4; ++k) {
            int c4 = c + 4 * k;
            float4 q = *(const float4*)(eT + 4 * c4);
            float x0 = X[4*c4+0][r], x1 = X[4*c4+1][r], x2 = X[4*c4+2][r], x3 = X[4*c4+3][r];
            float4 o;
            o.x = x0 + (q.x - x0);
            o.y = x1 + (q.y - x1);
            o.z = x2 + (q.z - x2);
            o.w = x3 + (q.w - x3);
            *(float4*)(out + OFF_Q + (size_t)(row0 + r) * DIM + 4 * c4) = o;
        }
    }
    if (t < RB) {
        int bi = bidx[t];
        out[OFF_IND + row0 + t] = (float)bi;
        ((int*)ws)[WS_IND + row0 + t] = bi;
        float v = bval[t];
        #pragma unroll
        for (int off = 1; off < 64; off <<= 1) v += __shfl_xor(v, off);
        if (t == 0) ws[WS_DIFFP + blockIdx.x] = v;
    }
}

// k_acc: wave-owned j-range histogram — NO atomics, race-free by partition.
// 16 waves/block; wave w exclusively owns j in [32w, 32w+32).
// Every wave scans the block's whole row chunk (j is wave-uniform per row ->
// scalar load + uniform branch); owned rows: 64 lanes do plain RMW on
// acc[j][lane] (lane-consecutive -> 2 lanes/bank -> conflict-free).
// Counts kept in registers: lane (j&31) increments.
__global__ __launch_bounds__(1024) void k_acc(
        const float* __restrict__ x,
        float* __restrict__ ws,
        int rows_per_blk) {
    __shared__ float acc[NJ * DIM];   // [j][d], 128 KB
    const int t = threadIdx.x;
    const int lane = t & 63, wid = t >> 6;
    for (int i = t; i < NJ * DIM; i += 1024) acc[i] = 0.f;
    __syncthreads();

    const int* __restrict__ ind = (const int*)ws + WS_IND;
    const int row0 = blockIdx.x * rows_per_blk;
    const int jlo = wid * 32, jhi = jlo + 32;

    float cnt = 0.f;   // lane l (<32) counts rows with j == jlo + l

    for (int r = 0; r < rows_per_blk; ++r) {
        int row = row0 + r;
        int j = ind[row];                      // wave-uniform
        if (j >= jlo && j < jhi) {             // uniform branch
            float v = x[(size_t)row * DIM + lane];
            acc[j * DIM + lane] += v;          // only this wave touches j
            cnt += (lane == (j & 31)) ? 1.f : 0.f;
        }
    }
    __syncthreads();

    float* part = ws + WS_PART + (size_t)blockIdx.x * PART_STRIDE;
    for (int i = t; i < NJ * DIM; i += 1024)
        part[i] = acc[i];
    if (lane < 32)
        part[NJ * DIM + jlo + lane] = cnt;     // disjoint j-ranges per wave
}

// k_red: sum nacc partials -> ESUM + CNT. Coalesced across threads per b.
__global__ void k_red(float* __restrict__ ws, int nacc) {
    int o = blockIdx.x * 256 + threadIdx.x;
    if (o >= PART_STRIDE) return;
    float s = 0.f;
    for (int b = 0; b < nacc; ++b)
        s += ws[WS_PART + (size_t)b * PART_STRIDE + o];
    if (o < NJ * DIM) ws[WS_ESUM + o] = s;
    else              ws[WS_CNT + (o - NJ * DIM)] = s;
}

// fallback (tiny ws): scan-per-code segment sum (correct, slow)
__global__ __launch_bounds__(256) void k_seg(
        const float* __restrict__ x,
        float* __restrict__ ws) {
    __shared__ float wsum[4][DIM];
    __shared__ float wcnt[4];
    const int j = blockIdx.x;
    const int t = threadIdx.x;
    const int lane = t & 63, wid = t >> 6;
    const int* __restrict__ ind = (const int*)ws + WS_IND;

    float acc[DIM];
    #pragma unroll
    for (int d = 0; d < DIM; ++d) acc[d] = 0.f;
    int cnt = 0;

    for (int i = 0; i < NROW / 4 / 256; ++i) {
        int r4 = i * 256 + t;
        int4 iv = *(const int4*)(ind + 4 * r4);
        int rows[4] = {4*r4, 4*r4+1, 4*r4+2, 4*r4+3};
        int js[4] = {iv.x, iv.y, iv.z, iv.w};
        #pragma unroll
        for (int k = 0; k < 4; ++k) {
            if (js[k] == j) {
                const float4* xr = (const float4*)(x + (size_t)rows[k] * DIM);
                #pragma unroll
                for (int q = 0; q < 16; ++q) {
                    float4 v = xr[q];
                    acc[4*q+0] += v.x; acc[4*q+1] += v.y;
                    acc[4*q+2] += v.z; acc[4*q+3] += v.w;
                }
                cnt++;
            }
        }
    }
    #pragma unroll
    for (int d = 0; d < DIM; ++d) {
        float v = acc[d];
        #pragma unroll
        for (int off = 1; off < 64; off <<= 1) v += __shfl_xor(v, off);
        if (lane == 0) wsum[wid][d] = v;
    }
    {
        float c = (float)cnt;
        #pragma unroll
        for (int off = 1; off < 64; off <<= 1) c += __shfl_xor(c, off);
        if (lane == 0) wcnt[wid] = c;
    }
    __syncthreads();
    if (t < DIM) {
        float s = wsum[0][t] + wsum[1][t] + wsum[2][t] + wsum[3][t];
        ws[WS_ESUM + (size_t)j * DIM + t] = s;
        if (t == 0) ws[WS_CNT + j] = wcnt[0] + wcnt[1] + wcnt[2] + wcnt[3];
    }
}

// k2a: new_cluster_size, n, total diff
__global__ void k2a(const float* __restrict__ cluster_size,
                    float* __restrict__ ws, float* __restrict__ out) {
    __shared__ float part[8];
    __shared__ float dpart[8];
    int j = threadIdx.x;  // 512 threads
    float ncs = cluster_size[j] * DECAY + ONE_MINUS_DECAY * ws[WS_CNT + j];
    out[OFF_NCS + j] = ncs;
    float4 dp = *(const float4*)(ws + WS_DIFFP + 4 * j);
    float dv = dp.x + dp.y + dp.z + dp.w;
    float v = ncs;
    #pragma unroll
    for (int off = 1; off < 64; off <<= 1) {
        v  += __shfl_xor(v, off);
        dv += __shfl_xor(dv, off);
    }
    if ((j & 63) == 0) { part[j >> 6] = v; dpart[j >> 6] = dv; }
    __syncthreads();
    if (j == 0) {
        float n = 0.f, dt = 0.f;
        #pragma unroll
        for (int w = 0; w < 8; ++w) { n += part[w]; dt += dpart[w]; }
        ws[WS_N] = n;
        ws[WS_DIFF] = dt;
    }
}

// k2b: new_embed_avg, new_embed, diff
__global__ void k2b(const float* __restrict__ embed_avg,
                    const float* __restrict__ ws,
                    float* __restrict__ out) {
    int i4 = blockIdx.x * 256 + threadIdx.x;  // 0..8191
    int base = i4 * 4;
    int d  = base >> 9;
    int j0 = base & 511;
    float n = ws[WS_N];
    float denom = n + (float)NJ * EPS;
    float4 avg = *(const float4*)(embed_avg + base);
    float a[4] = {avg.x, avg.y, avg.z, avg.w};
    float4 nea, ne;
    float* pa = &nea.x;
    float* pe = &ne.x;
    #pragma unroll
    for (int k = 0; k < 4; ++k) {
        int j = j0 + k;
        float es  = ws[WS_ESUM + (size_t)j * DIM + d];
        float na  = a[k] * DECAY + ONE_MINUS_DECAY * es;
        float ncs = out[OFF_NCS + j];
        float cs  = (ncs + EPS) / denom * n;
        pa[k] = na;
        pe[k] = na / cs;
    }
    *(float4*)(out + OFF_NEA + base) = nea;
    *(float4*)(out + OFF_NE  + base) = ne;
    if (i4 == 0) out[OFF_DIFF] = ws[WS_DIFF] * (1.0f / 8388608.0f);
}

extern "C" void kernel_launch(void* const* d_in, const int* in_sizes, int n_in,
                              void* d_out, int out_size, void* d_ws, size_t ws_size,
                              hipStream_t stream) {
    const float* x            = (const float*)d_in[0];
    const float* embed        = (const float*)d_in[1];
    const float* cluster_size = (const float*)d_in[2];
    const float* embed_avg    = (const float*)d_in[3];
    float* out = (float*)d_out;
    float* ws  = (float*)d_ws;

    // pick nacc (power of 2, <=256 -> all CUs) so partials fit in ws
    size_t ws_floats = ws_size / 4;
    size_t avail = ws_floats > WS_PART ? ws_floats - WS_PART : 0;
    int nacc = 256;
    while (nacc > 1 && (size_t)nacc * PART_STRIDE > avail) nacc >>= 1;
    bool use_acc = (size_t)nacc * PART_STRIDE <= avail;

    k0_prep<<<2, 256, 0, stream>>>(embed, ws);
    k1_main<<<NROW / RB, 256, 0, stream>>>(x, embed, ws, out);
    if (use_acc) {
        k_acc<<<nacc, 1024, 0, stream>>>(x, ws, NROW / nacc);
        k_red<<<(PART_STRIDE + 255) / 256, 256, 0, stream>>>(ws, nacc);
    } else {
        k_seg<<<NJ, 256, 0, stream>>>(x, ws);
    }
    k2a<<<1, 512, 0, stream>>>(cluster_size, ws, out);
    k2b<<<32, 256, 0, stream>>>(embed_avg, ws, out);
}

// Round 9
// 328.800 us; speedup vs baseline: 2.4576x; 1.0482x over previous
//
#include <hip/hip_runtime.h>

#define DECAY 0.99f
#define ONE_MINUS_DECAY 0.01f
#define EPS 1e-5f

#define NROW 131072
#define DIM 64
#define NJ 512
#define RB 64     // rows per block (k1)
#define JT 128    // j-tile width (k1)

// d_out offsets (floats), in reference return order
#define OFF_Q    0          // quantize_st: 8388608
#define OFF_DIFF 8388608    // diff scalar
#define OFF_IND  8388609    // embed_ind: 131072
#define OFF_NE   8519681    // new_embed: 64*512
#define OFF_NCS  8552449    // new_cluster_size: 512
#define OFF_NEA  8552961    // new_embed_avg: 64*512

// ws offsets (floats)
#define WS_QNORM 0          // 512
#define WS_EMBT  512        // embed^T: 512*64
#define WS_ESUM  33280      // embed_sum^T: 512*64 (code-major)
#define WS_CNT   66048      // 512
#define WS_DIFF  66560      // 1
#define WS_N     66561      // 1
#define WS_DIFFP 66564      // 2048 per-block diff partials
#define WS_IND   68612      // 131072 ints
#define WS_PART  199684     // nacc * 33280 partials ([j][d] sums + counts)
#define PART_STRIDE 33280

// kernel0: embed^T (code-major rows) + column norms
__global__ void k0_prep(const float* __restrict__ embed, float* __restrict__ ws) {
    int j = blockIdx.x * 256 + threadIdx.x;
    if (j < NJ) {
        float q = 0.f;
        #pragma unroll
        for (int d = 0; d < DIM; ++d) {
            float v = embed[d * NJ + j];
            q += v * v;
            ws[WS_EMBT + j * DIM + d] = v;
        }
        ws[WS_QNORM + j] = q;
    }
}

// kernel1: distances, argmin, quantize, ind, per-block diff partial. NO atomics.
// Thread (tx,ty) owns cols {4tx..4tx+3, 64+4tx..64+4tx+3} of the jt-tile:
// E ds_read_b128 lane stride = 4 floats -> banks 2-way aliased (free),
// vs the old 8tx layout's 4-way conflict (was 19% of k1 cycles).
__global__ __launch_bounds__(256) void k1_main(
        const float* __restrict__ x,
        const float* __restrict__ embed,
        float* __restrict__ ws,
        float* __restrict__ out) {
    __shared__ float X[DIM][RB + 1];
    __shared__ float E[DIM][JT];
    __shared__ float qn[NJ];
    __shared__ float xn[RB];
    __shared__ float bval[RB];
    __shared__ int   bidx[RB];

    const int t = threadIdx.x;
    const int row0 = blockIdx.x * RB;

    #pragma unroll
    for (int k = 0; k < 4; ++k) {
        int f = t + 256 * k;
        int r = f >> 4, c4 = f & 15;
        float4 v = *(const float4*)(x + (size_t)(row0 + r) * DIM + 4 * c4);
        X[4*c4 + 0][r] = v.x;
        X[4*c4 + 1][r] = v.y;
        X[4*c4 + 2][r] = v.z;
        X[4*c4 + 3][r] = v.w;
    }
    if (t < 128) {
        *(float4*)&qn[4 * t] = *(const float4*)(ws + WS_QNORM + 4 * t);
    }
    __syncthreads();
    if (t < RB) {
        float s = 0.f;
        #pragma unroll
        for (int d = 0; d < DIM; ++d) { float v = X[d][t]; s += v * v; }
        xn[t] = s;
    }

    const int tx = t & 15, ty = t >> 4;
    float best[4];
    int   besti[4];
    #pragma unroll
    for (int r = 0; r < 4; ++r) { best[r] = 3.4e38f; besti[r] = 0; }

    for (int jt = 0; jt < NJ / JT; ++jt) {
        __syncthreads();
        #pragma unroll
        for (int k = 0; k < 8; ++k) {
            int f = t + 256 * k;
            int d = f >> 5, c4 = f & 31;
            *(float4*)&E[d][4 * c4] =
                *(const float4*)(embed + (size_t)d * NJ + jt * JT + 4 * c4);
        }
        __syncthreads();

        float acc[4][8];
        #pragma unroll
        for (int r = 0; r < 4; ++r)
            #pragma unroll
            for (int c = 0; c < 8; ++c) acc[r][c] = 0.f;

        #pragma unroll 4
        for (int d = 0; d < DIM; ++d) {
            float4 xv = *(float4*)&X[d][4 * ty];
            float4 e0 = *(float4*)&E[d][4 * tx];        // cols 4tx..4tx+3
            float4 e1 = *(float4*)&E[d][64 + 4 * tx];   // cols 64+4tx..
            float xs[4] = {xv.x, xv.y, xv.z, xv.w};
            float es[8] = {e0.x, e0.y, e0.z, e0.w, e1.x, e1.y, e1.z, e1.w};
            #pragma unroll
            for (int r = 0; r < 4; ++r)
                #pragma unroll
                for (int c = 0; c < 8; ++c)
                    acc[r][c] = fmaf(xs[r], es[c], acc[r][c]);
        }

        #pragma unroll
        for (int r = 0; r < 4; ++r) {
            float xnr = xn[4 * ty + r];
            #pragma unroll
            for (int c = 0; c < 8; ++c) {
                int col = (c < 4) ? (4 * tx + c) : (60 + 4 * tx + c); // c-4+64
                int j = jt * JT + col;
                float dv = (xnr - 2.f * acc[r][c]) + qn[j];
                if (dv < best[r]) { best[r] = dv; besti[r] = j; }
            }
        }
    }

    #pragma unroll
    for (int r = 0; r < 4; ++r) {
        float bv = best[r];
        int   bi = besti[r];
        #pragma unroll
        for (int off = 1; off < 16; off <<= 1) {
            float ov = __shfl_xor(bv, off);
            int   oi = __shfl_xor(bi, off);
            if (ov < bv || (ov == bv && oi < bi)) { bv = ov; bi = oi; }
        }
        if (tx == 0) { bval[4 * ty + r] = bv; bidx[4 * ty + r] = bi; }
    }
    __syncthreads();

    {
        int r = t >> 2, c = t & 3;
        int bi = bidx[r];
        const float* eT = ws + WS_EMBT + (size_t)bi * DIM;
        #pragma unroll
        for (int k = 0; k < 4; ++k) {
            int c4 = c + 4 * k;
            float4 q = *(const float4*)(eT + 4 * c4);
            float x0 = X[4*c4+0][r], x1 = X[4*c4+1][r], x2 = X[4*c4+2][r], x3 = X[4*c4+3][r];
            float4 o;
            o.x = x0 + (q.x - x0);
            o.y = x1 + (q.y - x1);
            o.z = x2 + (q.z - x2);
            o.w = x3 + (q.w - x3);
            *(float4*)(out + OFF_Q + (size_t)(row0 + r) * DIM + 4 * c4) = o;
        }
    }
    if (t < RB) {
        int bi = bidx[t];
        out[OFF_IND + row0 + t] = (float)bi;
        ((int*)ws)[WS_IND + row0 + t] = bi;
        float v = bval[t];
        #pragma unroll
        for (int off = 1; off < 64; off <<= 1) v += __shfl_xor(v, off);
        if (t == 0) ws[WS_DIFFP + blockIdx.x] = v;
    }
}

// k_acc: wave-owned j-range histogram — NO atomics, race-free by partition.
// 16 waves/block; wave w exclusively owns j in [32w, 32w+32).
// Scan vectorized: 64 indices loaded per-lane in ONE coalesced load, then
// broadcast via __shfl (readlane) — replaces 512 dependent scalar loads.
__global__ __launch_bounds__(1024) void k_acc(
        const float* __restrict__ x,
        float* __restrict__ ws,
        int rows_per_blk) {
    __shared__ float acc[NJ * DIM];   // [j][d], 128 KB
    const int t = threadIdx.x;
    const int lane = t & 63, wid = t >> 6;
    for (int i = t; i < NJ * DIM; i += 1024) acc[i] = 0.f;
    __syncthreads();

    const int* __restrict__ ind = (const int*)ws + WS_IND;
    const int row0 = blockIdx.x * rows_per_blk;
    const int jlo = wid * 32, jhi = jlo + 32;

    float cnt = 0.f;   // lane l (<32) counts rows with j == jlo + l

    for (int base = 0; base < rows_per_blk; base += 64) {
        int j64 = ind[row0 + base + lane];     // coalesced 256B load
        #pragma unroll
        for (int r2 = 0; r2 < 64; ++r2) {
            int j = __shfl(j64, r2);           // wave-uniform broadcast
            if (j >= jlo && j < jhi) {         // uniform branch
                int row = row0 + base + r2;
                float v = x[(size_t)row * DIM + lane];
                acc[j * DIM + lane] += v;      // only this wave touches j
                cnt += (lane == (j & 31)) ? 1.f : 0.f;
            }
        }
    }
    __syncthreads();

    float* part = ws + WS_PART + (size_t)blockIdx.x * PART_STRIDE;
    for (int i = t; i < NJ * DIM; i += 1024)
        part[i] = acc[i];
    if (lane < 32)
        part[NJ * DIM + jlo + lane] = cnt;     // disjoint j-ranges per wave
}

// k_red: sum nacc partials -> ESUM + CNT. Coalesced across threads per b.
__global__ void k_red(float* __restrict__ ws, int nacc) {
    int o = blockIdx.x * 256 + threadIdx.x;
    if (o >= PART_STRIDE) return;
    float s = 0.f;
    for (int b = 0; b < nacc; ++b)
        s += ws[WS_PART + (size_t)b * PART_STRIDE + o];
    if (o < NJ * DIM) ws[WS_ESUM + o] = s;
    else              ws[WS_CNT + (o - NJ * DIM)] = s;
}

// fallback (tiny ws): scan-per-code segment sum (correct, slow)
__global__ __launch_bounds__(256) void k_seg(
        const float* __restrict__ x,
        float* __restrict__ ws) {
    __shared__ float wsum[4][DIM];
    __shared__ float wcnt[4];
    const int j = blockIdx.x;
    const int t = threadIdx.x;
    const int lane = t & 63, wid = t >> 6;
    const int* __restrict__ ind = (const int*)ws + WS_IND;

    float acc[DIM];
    #pragma unroll
    for (int d = 0; d < DIM; ++d) acc[d] = 0.f;
    int cnt = 0;

    for (int i = 0; i < NROW / 4 / 256; ++i) {
        int r4 = i * 256 + t;
        int4 iv = *(const int4*)(ind + 4 * r4);
        int rows[4] = {4*r4, 4*r4+1, 4*r4+2, 4*r4+3};
        int js[4] = {iv.x, iv.y, iv.z, iv.w};
        #pragma unroll
        for (int k = 0; k < 4; ++k) {
            if (js[k] == j) {
                const float4* xr = (const float4*)(x + (size_t)rows[k] * DIM);
                #pragma unroll
                for (int q = 0; q < 16; ++q) {
                    float4 v = xr[q];
                    acc[4*q+0] += v.x; acc[4*q+1] += v.y;
                    acc[4*q+2] += v.z; acc[4*q+3] += v.w;
                }
                cnt++;
            }
        }
    }
    #pragma unroll
    for (int d = 0; d < DIM; ++d) {
        float v = acc[d];
        #pragma unroll
        for (int off = 1; off < 64; off <<= 1) v += __shfl_xor(v, off);
        if (lane == 0) wsum[wid][d] = v;
    }
    {
        float c = (float)cnt;
        #pragma unroll
        for (int off = 1; off < 64; off <<= 1) c += __shfl_xor(c, off);
        if (lane == 0) wcnt[wid] = c;
    }
    __syncthreads();
    if (t < DIM) {
        float s = wsum[0][t] + wsum[1][t] + wsum[2][t] + wsum[3][t];
        ws[WS_ESUM + (size_t)j * DIM + t] = s;
        if (t == 0) ws[WS_CNT + j] = wcnt[0] + wcnt[1] + wcnt[2] + wcnt[3];
    }
}

// k2a: new_cluster_size, n, total diff
__global__ void k2a(const float* __restrict__ cluster_size,
                    float* __restrict__ ws, float* __restrict__ out) {
    __shared__ float part[8];
    __shared__ float dpart[8];
    int j = threadIdx.x;  // 512 threads
    float ncs = cluster_size[j] * DECAY + ONE_MINUS_DECAY * ws[WS_CNT + j];
    out[OFF_NCS + j] = ncs;
    float4 dp = *(const float4*)(ws + WS_DIFFP + 4 * j);
    float dv = dp.x + dp.y + dp.z + dp.w;
    float v = ncs;
    #pragma unroll
    for (int off = 1; off < 64; off <<= 1) {
        v  += __shfl_xor(v, off);
        dv += __shfl_xor(dv, off);
    }
    if ((j & 63) == 0) { part[j >> 6] = v; dpart[j >> 6] = dv; }
    __syncthreads();
    if (j == 0) {
        float n = 0.f, dt = 0.f;
        #pragma unroll
        for (int w = 0; w < 8; ++w) { n += part[w]; dt += dpart[w]; }
        ws[WS_N] = n;
        ws[WS_DIFF] = dt;
    }
}

// k2b: new_embed_avg, new_embed, diff
__global__ void k2b(const float* __restrict__ embed_avg,
                    const float* __restrict__ ws,
                    float* __restrict__ out) {
    int i4 = blockIdx.x * 256 + threadIdx.x;  // 0..8191
    int base = i4 * 4;
    int d  = base >> 9;
    int j0 = base & 511;
    float n = ws[WS_N];
    float denom = n + (float)NJ * EPS;
    float4 avg = *(const float4*)(embed_avg + base);
    float a[4] = {avg.x, avg.y, avg.z, avg.w};
    float4 nea, ne;
    float* pa = &nea.x;
    float* pe = &ne.x;
    #pragma unroll
    for (int k = 0; k < 4; ++k) {
        int j = j0 + k;
        float es  = ws[WS_ESUM + (size_t)j * DIM + d];
        float na  = a[k] * DECAY + ONE_MINUS_DECAY * es;
        float ncs = out[OFF_NCS + j];
        float cs  = (ncs + EPS) / denom * n;
        pa[k] = na;
        pe[k] = na / cs;
    }
    *(float4*)(out + OFF_NEA + base) = nea;
    *(float4*)(out + OFF_NE  + base) = ne;
    if (i4 == 0) out[OFF_DIFF] = ws[WS_DIFF] * (1.0f / 8388608.0f);
}

extern "C" void kernel_launch(void* const* d_in, const int* in_sizes, int n_in,
                              void* d_out, int out_size, void* d_ws, size_t ws_size,
                              hipStream_t stream) {
    const float* x            = (const float*)d_in[0];
    const float* embed        = (const float*)d_in[1];
    const float* cluster_size = (const float*)d_in[2];
    const float* embed_avg    = (const float*)d_in[3];
    float* out = (float*)d_out;
    float* ws  = (float*)d_ws;

    // pick nacc (power of 2, <=256 -> all CUs) so partials fit in ws
    size_t ws_floats = ws_size / 4;
    size_t avail = ws_floats > WS_PART ? ws_floats - WS_PART : 0;
    int nacc = 256;
    while (nacc > 1 && (size_t)nacc * PART_STRIDE > avail) nacc >>= 1;
    bool use_acc = (size_t)nacc * PART_STRIDE <= avail;

    k0_prep<<<2, 256, 0, stream>>>(embed, ws);
    k1_main<<<NROW / RB, 256, 0, stream>>>(x, embed, ws, out);
    if (use_acc) {
        k_acc<<<nacc, 1024, 0, stream>>>(x, ws, NROW / nacc);
        k_red<<<(PART_STRIDE + 255) / 256, 256, 0, stream>>>(ws, nacc);
    } else {
        k_seg<<<NJ, 256, 0, stream>>>(x, ws);
    }
    k2a<<<1, 512, 0, stream>>>(cluster_size, ws, out);
    k2b<<<32, 256, 0, stream>>>(embed_avg, ws, out);
}

// Round 10
// 283.492 us; speedup vs baseline: 2.8503x; 1.1598x over previous
//
#include <hip/hip_runtime.h>

#define DECAY 0.99f
#define ONE_MINUS_DECAY 0.01f
#define EPS 1e-5f

#define NROW 131072
#define DIM 64
#define NJ 512
#define RB 128    // rows per block (k1)
#define JT 256    // j-tile width (k1), 2 tiles
#define NBLK1 (NROW / RB)   // 1024

// d_out offsets (floats), in reference return order
#define OFF_Q    0          // quantize_st: 8388608
#define OFF_DIFF 8388608    // diff scalar
#define OFF_IND  8388609    // embed_ind: 131072
#define OFF_NE   8519681    // new_embed: 64*512
#define OFF_NCS  8552449    // new_cluster_size: 512
#define OFF_NEA  8552961    // new_embed_avg: 64*512

// ws offsets (floats)
#define WS_QNORM 0          // 512
#define WS_EMBT  512        // embed^T: 512*64
#define WS_ESUM  33280      // embed_sum^T: 512*64 (code-major)
#define WS_CNT   66048      // 512
#define WS_DIFF  66560      // 1
#define WS_N     66561      // 1
#define WS_DIFFP 66564      // per-block diff partials (NBLK1 used)
#define WS_IND   68612      // 131072 ints
#define WS_PART  199684     // nacc * 33280 partials ([j][d] sums + counts)
#define PART_STRIDE 33280

// kernel0: embed^T (code-major rows) + column norms
__global__ void k0_prep(const float* __restrict__ embed, float* __restrict__ ws) {
    int j = blockIdx.x * 256 + threadIdx.x;
    if (j < NJ) {
        float q = 0.f;
        #pragma unroll
        for (int d = 0; d < DIM; ++d) {
            float v = embed[d * NJ + j];
            q += v * v;
            ws[WS_EMBT + j * DIM + d] = v;
        }
        ws[WS_QNORM + j] = q;
    }
}

// kernel1: 8x16 per-thread tile -> LDS traffic 0.1875 B/FMA (was 0.375),
// CU LDS demand/d (192 cyc) < VALU FMA/d (256 cyc) => FMA-bound.
// X-fragment reads are ty-broadcast (free); E-fragment 4tx stride = 2-way (free).
__global__ __launch_bounds__(256) void k1_main(
        const float* __restrict__ x,
        const float* __restrict__ embed,
        float* __restrict__ ws,
        float* __restrict__ out) {
    __shared__ float X[DIM][RB + 1];   // 33 KB
    __shared__ float E[DIM][JT];       // 64 KB
    __shared__ float qn[NJ];
    __shared__ float xn[RB];
    __shared__ float bval[RB];
    __shared__ int   bidx[RB];
    __shared__ float dred[2];

    const int t = threadIdx.x;
    const int row0 = blockIdx.x * RB;

    // load X: 128 rows x 16 float4, coalesced; transposed LDS write ~2-way
    #pragma unroll
    for (int k = 0; k < 8; ++k) {
        int f = t + 256 * k;
        int r = f >> 4, c4 = f & 15;
        float4 v = *(const float4*)(x + (size_t)(row0 + r) * DIM + 4 * c4);
        X[4*c4 + 0][r] = v.x;
        X[4*c4 + 1][r] = v.y;
        X[4*c4 + 2][r] = v.z;
        X[4*c4 + 3][r] = v.w;
    }
    if (t < 128) {
        *(float4*)&qn[4 * t] = *(const float4*)(ws + WS_QNORM + 4 * t);
    }
    __syncthreads();
    if (t < 128) {
        float s = 0.f;
        #pragma unroll
        for (int d = 0; d < DIM; ++d) { float v = X[d][t]; s += v * v; }
        xn[t] = s;
    }

    const int tx = t & 15, ty = t >> 4;   // 16 col-groups x 16 row-groups
    float best[8];
    int   besti[8];
    #pragma unroll
    for (int r = 0; r < 8; ++r) { best[r] = 3.4e38f; besti[r] = 0; }

    for (int jt = 0; jt < NJ / JT; ++jt) {
        __syncthreads();   // prev compute done (and xn visible on first iter)
        // load E tile: 64 x 256 floats, coalesced
        #pragma unroll
        for (int k = 0; k < 16; ++k) {
            int f = t + 256 * k;
            int d = f >> 6, c4 = f & 63;
            *(float4*)&E[d][4 * c4] =
                *(const float4*)(embed + (size_t)d * NJ + jt * JT + 4 * c4);
        }
        __syncthreads();

        float acc[8][16];
        #pragma unroll
        for (int r = 0; r < 8; ++r)
            #pragma unroll
            for (int c = 0; c < 16; ++c) acc[r][c] = 0.f;

        #pragma unroll 2
        for (int d = 0; d < DIM; ++d) {
            float4 x0 = *(float4*)&X[d][4 * ty];        // rows 4ty..   (broadcast)
            float4 x1 = *(float4*)&X[d][64 + 4 * ty];   // rows 64+4ty..
            float4 e0 = *(float4*)&E[d][4 * tx];        // cols 4tx..
            float4 e1 = *(float4*)&E[d][64 + 4 * tx];
            float4 e2 = *(float4*)&E[d][128 + 4 * tx];
            float4 e3 = *(float4*)&E[d][192 + 4 * tx];
            float xs[8] = {x0.x, x0.y, x0.z, x0.w, x1.x, x1.y, x1.z, x1.w};
            float es[16] = {e0.x, e0.y, e0.z, e0.w, e1.x, e1.y, e1.z, e1.w,
                            e2.x, e2.y, e2.z, e2.w, e3.x, e3.y, e3.z, e3.w};
            #pragma unroll
            for (int r = 0; r < 8; ++r)
                #pragma unroll
                for (int c = 0; c < 16; ++c)
                    acc[r][c] = fmaf(xs[r], es[c], acc[r][c]);
        }

        #pragma unroll
        for (int r = 0; r < 8; ++r) {
            int row_r = (r < 4) ? (4 * ty + r) : (64 + 4 * ty + (r - 4));
            float xnr = xn[row_r];
            #pragma unroll
            for (int c = 0; c < 16; ++c) {
                int j = jt * JT + (c >> 2) * 64 + 4 * tx + (c & 3);
                float dv = (xnr - 2.f * acc[r][c]) + qn[j];
                if (dv < best[r]) { best[r] = dv; besti[r] = j; }
            }
        }
    }

    // reduce argmin across the 16 tx lanes sharing each row-group
    #pragma unroll
    for (int r = 0; r < 8; ++r) {
        float bv = best[r];
        int   bi = besti[r];
        #pragma unroll
        for (int off = 1; off < 16; off <<= 1) {
            float ov = __shfl_xor(bv, off);
            int   oi = __shfl_xor(bi, off);
            if (ov < bv || (ov == bv && oi < bi)) { bv = ov; bi = oi; }
        }
        if (tx == 0) {
            int row_r = (r < 4) ? (4 * ty + r) : (64 + 4 * ty + (r - 4));
            bval[row_r] = bv; bidx[row_r] = bi;
        }
    }
    __syncthreads();

    // quantize write (x + (q - x) matches reference rounding)
    {
        int r = t >> 1, cc = t & 1;
        int bi = bidx[r];
        const float* eT = ws + WS_EMBT + (size_t)bi * DIM;
        #pragma unroll
        for (int k = 0; k < 8; ++k) {
            int c4 = cc + 2 * k;
            float4 q = *(const float4*)(eT + 4 * c4);
            float x0 = X[4*c4+0][r], x1 = X[4*c4+1][r], x2 = X[4*c4+2][r], x3 = X[4*c4+3][r];
            float4 o;
            o.x = x0 + (q.x - x0);
            o.y = x1 + (q.y - x1);
            o.z = x2 + (q.z - x2);
            o.w = x3 + (q.w - x3);
            *(float4*)(out + OFF_Q + (size_t)(row0 + r) * DIM + 4 * c4) = o;
        }
    }
    // indices + per-block diff partial
    if (t < 128) {
        int bi = bidx[t];
        out[OFF_IND + row0 + t] = (float)bi;
        ((int*)ws)[WS_IND + row0 + t] = bi;
        float v = bval[t];
        #pragma unroll
        for (int off = 1; off < 64; off <<= 1) v += __shfl_xor(v, off);
        if ((t & 63) == 0) dred[t >> 6] = v;
    }
    __syncthreads();
    if (t == 0) ws[WS_DIFFP + blockIdx.x] = dred[0] + dred[1];
}

// k_acc: wave-owned j-range histogram — NO atomics, race-free by partition.
// Ballot skip-scan: visit only owned rows (~2 per 64-row batch per wave)
// instead of 64 branch iterations.
__global__ __launch_bounds__(1024) void k_acc(
        const float* __restrict__ x,
        float* __restrict__ ws,
        int rows_per_blk) {
    __shared__ float acc[NJ * DIM];   // [j][d], 128 KB
    const int t = threadIdx.x;
    const int lane = t & 63, wid = t >> 6;
    for (int i = t; i < NJ * DIM; i += 1024) acc[i] = 0.f;
    __syncthreads();

    const int* __restrict__ ind = (const int*)ws + WS_IND;
    const int row0 = blockIdx.x * rows_per_blk;
    const int jlo = wid * 32, jhi = jlo + 32;

    float cnt = 0.f;   // lane l (<32) counts rows with j == jlo + l

    for (int base = 0; base < rows_per_blk; base += 64) {
        int j64 = ind[row0 + base + lane];               // coalesced 256B load
        unsigned long long owned = __ballot(j64 >= jlo && j64 < jhi);
        while (owned) {
            int r2 = __ffsll(owned) - 1;
            owned &= owned - 1;
            int j = __shfl(j64, r2);                     // wave-uniform
            float v = x[(size_t)(row0 + base + r2) * DIM + lane];
            acc[j * DIM + lane] += v;                    // only this wave touches j
            cnt += (lane == (j & 31)) ? 1.f : 0.f;
        }
    }
    __syncthreads();

    float* part = ws + WS_PART + (size_t)blockIdx.x * PART_STRIDE;
    for (int i = t; i < NJ * DIM; i += 1024)
        part[i] = acc[i];
    if (lane < 32)
        part[NJ * DIM + jlo + lane] = cnt;     // disjoint j-ranges per wave
}

// k_red: sum nacc partials -> ESUM + CNT. 8 independent chains => 8 loads in flight.
__global__ void k_red(float* __restrict__ ws, int nacc) {
    int o = blockIdx.x * 256 + threadIdx.x;
    if (o >= PART_STRIDE) return;
    const float* p = ws + WS_PART + o;
    float s0 = 0.f, s1 = 0.f, s2 = 0.f, s3 = 0.f;
    float s4 = 0.f, s5 = 0.f, s6 = 0.f, s7 = 0.f;
    int b = 0;
    for (; b + 8 <= nacc; b += 8) {
        s0 += p[(size_t)(b+0) * PART_STRIDE];
        s1 += p[(size_t)(b+1) * PART_STRIDE];
        s2 += p[(size_t)(b+2) * PART_STRIDE];
        s3 += p[(size_t)(b+3) * PART_STRIDE];
        s4 += p[(size_t)(b+4) * PART_STRIDE];
        s5 += p[(size_t)(b+5) * PART_STRIDE];
        s6 += p[(size_t)(b+6) * PART_STRIDE];
        s7 += p[(size_t)(b+7) * PART_STRIDE];
    }
    for (; b < nacc; ++b) s0 += p[(size_t)b * PART_STRIDE];
    float s = ((s0 + s1) + (s2 + s3)) + ((s4 + s5) + (s6 + s7));
    if (o < NJ * DIM) ws[WS_ESUM + o] = s;
    else              ws[WS_CNT + (o - NJ * DIM)] = s;
}

// fallback (tiny ws): scan-per-code segment sum (correct, slow)
__global__ __launch_bounds__(256) void k_seg(
        const float* __restrict__ x,
        float* __restrict__ ws) {
    __shared__ float wsum[4][DIM];
    __shared__ float wcnt[4];
    const int j = blockIdx.x;
    const int t = threadIdx.x;
    const int lane = t & 63, wid = t >> 6;
    const int* __restrict__ ind = (const int*)ws + WS_IND;

    float acc[DIM];
    #pragma unroll
    for (int d = 0; d < DIM; ++d) acc[d] = 0.f;
    int cnt = 0;

    for (int i = 0; i < NROW / 4 / 256; ++i) {
        int r4 = i * 256 + t;
        int4 iv = *(const int4*)(ind + 4 * r4);
        int rows[4] = {4*r4, 4*r4+1, 4*r4+2, 4*r4+3};
        int js[4] = {iv.x, iv.y, iv.z, iv.w};
        #pragma unroll
        for (int k = 0; k < 4; ++k) {
            if (js[k] == j) {
                const float4* xr = (const float4*)(x + (size_t)rows[k] * DIM);
                #pragma unroll
                for (int q = 0; q < 16; ++q) {
                    float4 v = xr[q];
                    acc[4*q+0] += v.x; acc[4*q+1] += v.y;
                    acc[4*q+2] += v.z; acc[4*q+3] += v.w;
                }
                cnt++;
            }
        }
    }
    #pragma unroll
    for (int d = 0; d < DIM; ++d) {
        float v = acc[d];
        #pragma unroll
        for (int off = 1; off < 64; off <<= 1) v += __shfl_xor(v, off);
        if (lane == 0) wsum[wid][d] = v;
    }
    {
        float c = (float)cnt;
        #pragma unroll
        for (int off = 1; off < 64; off <<= 1) c += __shfl_xor(c, off);
        if (lane == 0) wcnt[wid] = c;
    }
    __syncthreads();
    if (t < DIM) {
        float s = wsum[0][t] + wsum[1][t] + wsum[2][t] + wsum[3][t];
        ws[WS_ESUM + (size_t)j * DIM + t] = s;
        if (t == 0) ws[WS_CNT + j] = wcnt[0] + wcnt[1] + wcnt[2] + wcnt[3];
    }
}

// k2a: new_cluster_size, n, total diff (NBLK1=1024 diff partials -> float2)
__global__ void k2a(const float* __restrict__ cluster_size,
                    float* __restrict__ ws, float* __restrict__ out) {
    __shared__ float part[8];
    __shared__ float dpart[8];
    int j = threadIdx.x;  // 512 threads
    float ncs = cluster_size[j] * DECAY + ONE_MINUS_DECAY * ws[WS_CNT + j];
    out[OFF_NCS + j] = ncs;
    float2 dp = *(const float2*)(ws + WS_DIFFP + 2 * j);
    float dv = dp.x + dp.y;
    float v = ncs;
    #pragma unroll
    for (int off = 1; off < 64; off <<= 1) {
        v  += __shfl_xor(v, off);
        dv += __shfl_xor(dv, off);
    }
    if ((j & 63) == 0) { part[j >> 6] = v; dpart[j >> 6] = dv; }
    __syncthreads();
    if (j == 0) {
        float n = 0.f, dt = 0.f;
        #pragma unroll
        for (int w = 0; w < 8; ++w) { n += part[w]; dt += dpart[w]; }
        ws[WS_N] = n;
        ws[WS_DIFF] = dt;
    }
}

// k2b: new_embed_avg, new_embed, diff
__global__ void k2b(const float* __restrict__ embed_avg,
                    const float* __restrict__ ws,
                    float* __restrict__ out) {
    int i4 = blockIdx.x * 256 + threadIdx.x;  // 0..8191
    int base = i4 * 4;
    int d  = base >> 9;
    int j0 = base & 511;
    float n = ws[WS_N];
    float denom = n + (float)NJ * EPS;
    float4 avg = *(const float4*)(embed_avg + base);
    float a[4] = {avg.x, avg.y, avg.z, avg.w};
    float4 nea, ne;
    float* pa = &nea.x;
    float* pe = &ne.x;
    #pragma unroll
    for (int k = 0; k < 4; ++k) {
        int j = j0 + k;
        float es  = ws[WS_ESUM + (size_t)j * DIM + d];
        float na  = a[k] * DECAY + ONE_MINUS_DECAY * es;
        float ncs = out[OFF_NCS + j];
        float cs  = (ncs + EPS) / denom * n;
        pa[k] = na;
        pe[k] = na / cs;
    }
    *(float4*)(out + OFF_NEA + base) = nea;
    *(float4*)(out + OFF_NE  + base) = ne;
    if (i4 == 0) out[OFF_DIFF] = ws[WS_DIFF] * (1.0f / 8388608.0f);
}

extern "C" void kernel_launch(void* const* d_in, const int* in_sizes, int n_in,
                              void* d_out, int out_size, void* d_ws, size_t ws_size,
                              hipStream_t stream) {
    const float* x            = (const float*)d_in[0];
    const float* embed        = (const float*)d_in[1];
    const float* cluster_size = (const float*)d_in[2];
    const float* embed_avg    = (const float*)d_in[3];
    float* out = (float*)d_out;
    float* ws  = (float*)d_ws;

    // pick nacc (power of 2, <=256 -> all CUs) so partials fit in ws
    size_t ws_floats = ws_size / 4;
    size_t avail = ws_floats > WS_PART ? ws_floats - WS_PART : 0;
    int nacc = 256;
    while (nacc > 1 && (size_t)nacc * PART_STRIDE > avail) nacc >>= 1;
    bool use_acc = (size_t)nacc * PART_STRIDE <= avail;

    k0_prep<<<2, 256, 0, stream>>>(embed, ws);
    k1_main<<<NBLK1, 256, 0, stream>>>(x, embed, ws, out);
    if (use_acc) {
        k_acc<<<nacc, 1024, 0, stream>>>(x, ws, NROW / nacc);
        k_red<<<(PART_STRIDE + 255) / 256, 256, 0, stream>>>(ws, nacc);
    } else {
        k_seg<<<NJ, 256, 0, stream>>>(x, ws);
    }
    k2a<<<1, 512, 0, stream>>>(cluster_size, ws, out);
    k2b<<<32, 256, 0, stream>>>(embed_avg, ws, out);
}

// Round 11
// 250.008 us; speedup vs baseline: 3.2321x; 1.1339x over previous
//
#include <hip/hip_runtime.h>

#define DECAY 0.99f
#define ONE_MINUS_DECAY 0.01f
#define EPS 1e-5f

#define NROW 131072
#define DIM 64
#define NJ 512
#define RB 128    // rows per block (k1)
#define JT 128    // j-tile width (k1), 4 tiles
#define NBLK1 (NROW / RB)   // 1024

// d_out offsets (floats), in reference return order
#define OFF_Q    0          // quantize_st: 8388608
#define OFF_DIFF 8388608    // diff scalar
#define OFF_IND  8388609    // embed_ind: 131072
#define OFF_NE   8519681    // new_embed: 64*512
#define OFF_NCS  8552449    // new_cluster_size: 512
#define OFF_NEA  8552961    // new_embed_avg: 64*512

// ws offsets (floats)
#define WS_QNORM 0          // 512
#define WS_EMBT  512        // embed^T: 512*64
#define WS_ESUM  33280      // embed_sum^T: 512*64 (code-major)
#define WS_CNT   66048      // 512
#define WS_DIFF  66560      // 1
#define WS_N     66561      // 1
#define WS_DIFFP 66564      // per-block diff partials (NBLK1 used)
#define WS_IND   68612      // 131072 ints
#define WS_PART  199684     // nacc * 33280 partials ([j][d] sums + counts)
#define PART_STRIDE 33280

// kernel0: embed^T (code-major rows) + column norms
__global__ void k0_prep(const float* __restrict__ embed, float* __restrict__ ws) {
    int j = blockIdx.x * 256 + threadIdx.x;
    if (j < NJ) {
        float q = 0.f;
        #pragma unroll
        for (int d = 0; d < DIM; ++d) {
            float v = embed[d * NJ + j];
            q += v * v;
            ws[WS_EMBT + j * DIM + d] = v;
        }
        ws[WS_QNORM + j] = q;
    }
}

// kernel1: 8x8 per-thread tile @ RB=128/JT=128 -> 69 KB LDS -> 2 blocks/CU
// (2 waves/SIMD: waves mutually hide LDS latency; R10's 102 KB/1-blk config
// had 1 wave/SIMD and stalled 120us despite lower traffic).
// X reads: 4 unique addrs/wave (16-way broadcast, conflict-free);
// E reads: stride 16B -> 2-way (free).
__global__ __launch_bounds__(256) void k1_main(
        const float* __restrict__ x,
        const float* __restrict__ embed,
        float* __restrict__ ws,
        float* __restrict__ out) {
    __shared__ float X[DIM][RB + 1];   // 33 KB
    __shared__ float E[DIM][JT];       // 32 KB
    __shared__ float qn[NJ];
    __shared__ float xn[RB];
    __shared__ float bval[RB];
    __shared__ int   bidx[RB];
    __shared__ float dred[2];

    const int t = threadIdx.x;
    const int row0 = blockIdx.x * RB;

    // load X: 128 rows x 16 float4, coalesced; transposed LDS write
    #pragma unroll
    for (int k = 0; k < 8; ++k) {
        int f = t + 256 * k;
        int r = f >> 4, c4 = f & 15;
        float4 v = *(const float4*)(x + (size_t)(row0 + r) * DIM + 4 * c4);
        X[4*c4 + 0][r] = v.x;
        X[4*c4 + 1][r] = v.y;
        X[4*c4 + 2][r] = v.z;
        X[4*c4 + 3][r] = v.w;
    }
    if (t < 128) {
        *(float4*)&qn[4 * t] = *(const float4*)(ws + WS_QNORM + 4 * t);
    }
    __syncthreads();
    if (t < 128) {
        float s = 0.f;
        #pragma unroll
        for (int d = 0; d < DIM; ++d) { float v = X[d][t]; s += v * v; }
        xn[t] = s;
    }

    const int tx = t & 15, ty = t >> 4;   // 16 col-groups x 16 row-groups
    float best[8];
    int   besti[8];
    #pragma unroll
    for (int r = 0; r < 8; ++r) { best[r] = 3.4e38f; besti[r] = 0; }

    for (int jt = 0; jt < NJ / JT; ++jt) {
        __syncthreads();   // prev compute done (and xn visible on first iter)
        // load E tile: 64 x 128 floats, coalesced
        #pragma unroll
        for (int k = 0; k < 8; ++k) {
            int f = t + 256 * k;
            int d = f >> 5, c4 = f & 31;
            *(float4*)&E[d][4 * c4] =
                *(const float4*)(embed + (size_t)d * NJ + jt * JT + 4 * c4);
        }
        __syncthreads();

        float acc[8][8];
        #pragma unroll
        for (int r = 0; r < 8; ++r)
            #pragma unroll
            for (int c = 0; c < 8; ++c) acc[r][c] = 0.f;

        #pragma unroll 4
        for (int d = 0; d < DIM; ++d) {
            float4 x0 = *(float4*)&X[d][4 * ty];        // rows 4ty..    (broadcast)
            float4 x1 = *(float4*)&X[d][64 + 4 * ty];   // rows 64+4ty..
            float4 e0 = *(float4*)&E[d][4 * tx];        // cols 4tx..
            float4 e1 = *(float4*)&E[d][64 + 4 * tx];   // cols 64+4tx..
            float xs[8] = {x0.x, x0.y, x0.z, x0.w, x1.x, x1.y, x1.z, x1.w};
            float es[8] = {e0.x, e0.y, e0.z, e0.w, e1.x, e1.y, e1.z, e1.w};
            #pragma unroll
            for (int r = 0; r < 8; ++r)
                #pragma unroll
                for (int c = 0; c < 8; ++c)
                    acc[r][c] = fmaf(xs[r], es[c], acc[r][c]);
        }

        #pragma unroll
        for (int r = 0; r < 8; ++r) {
            int row_r = (r < 4) ? (4 * ty + r) : (64 + 4 * ty + (r - 4));
            float xnr = xn[row_r];
            #pragma unroll
            for (int c = 0; c < 8; ++c) {
                int col = (c < 4) ? (4 * tx + c) : (64 + 4 * tx + (c - 4));
                int j = jt * JT + col;
                float dv = (xnr - 2.f * acc[r][c]) + qn[j];
                if (dv < best[r]) { best[r] = dv; besti[r] = j; }
            }
        }
    }

    // reduce argmin across the 16 tx lanes sharing each row-group
    #pragma unroll
    for (int r = 0; r < 8; ++r) {
        float bv = best[r];
        int   bi = besti[r];
        #pragma unroll
        for (int off = 1; off < 16; off <<= 1) {
            float ov = __shfl_xor(bv, off);
            int   oi = __shfl_xor(bi, off);
            if (ov < bv || (ov == bv && oi < bi)) { bv = ov; bi = oi; }
        }
        if (tx == 0) {
            int row_r = (r < 4) ? (4 * ty + r) : (64 + 4 * ty + (r - 4));
            bval[row_r] = bv; bidx[row_r] = bi;
        }
    }
    __syncthreads();

    // quantize write (x + (q - x) matches reference rounding)
    {
        int r = t >> 1, cc = t & 1;
        int bi = bidx[r];
        const float* eT = ws + WS_EMBT + (size_t)bi * DIM;
        #pragma unroll
        for (int k = 0; k < 8; ++k) {
            int c4 = cc + 2 * k;
            float4 q = *(const float4*)(eT + 4 * c4);
            float x0 = X[4*c4+0][r], x1 = X[4*c4+1][r], x2 = X[4*c4+2][r], x3 = X[4*c4+3][r];
            float4 o;
            o.x = x0 + (q.x - x0);
            o.y = x1 + (q.y - x1);
            o.z = x2 + (q.z - x2);
            o.w = x3 + (q.w - x3);
            *(float4*)(out + OFF_Q + (size_t)(row0 + r) * DIM + 4 * c4) = o;
        }
    }
    // indices + per-block diff partial
    if (t < 128) {
        int bi = bidx[t];
        out[OFF_IND + row0 + t] = (float)bi;
        ((int*)ws)[WS_IND + row0 + t] = bi;
        float v = bval[t];
        #pragma unroll
        for (int off = 1; off < 64; off <<= 1) v += __shfl_xor(v, off);
        if ((t & 63) == 0) dred[t >> 6] = v;
    }
    __syncthreads();
    if (t == 0) ws[WS_DIFFP + blockIdx.x] = dred[0] + dred[1];
}

// k_acc: wave-owned j-range histogram — NO atomics, race-free by partition.
// Ballot skip-scan: visit only owned rows (~2 per 64-row batch per wave).
__global__ __launch_bounds__(1024) void k_acc(
        const float* __restrict__ x,
        float* __restrict__ ws,
        int rows_per_blk) {
    __shared__ float acc[NJ * DIM];   // [j][d], 128 KB
    const int t = threadIdx.x;
    const int lane = t & 63, wid = t >> 6;
    for (int i = t; i < NJ * DIM; i += 1024) acc[i] = 0.f;
    __syncthreads();

    const int* __restrict__ ind = (const int*)ws + WS_IND;
    const int row0 = blockIdx.x * rows_per_blk;
    const int jlo = wid * 32, jhi = jlo + 32;

    float cnt = 0.f;   // lane l (<32) counts rows with j == jlo + l

    for (int base = 0; base < rows_per_blk; base += 64) {
        int j64 = ind[row0 + base + lane];               // coalesced 256B load
        unsigned long long owned = __ballot(j64 >= jlo && j64 < jhi);
        while (owned) {
            int r2 = __ffsll(owned) - 1;
            owned &= owned - 1;
            int j = __shfl(j64, r2);                     // wave-uniform
            float v = x[(size_t)(row0 + base + r2) * DIM + lane];
            acc[j * DIM + lane] += v;                    // only this wave touches j
            cnt += (lane == (j & 31)) ? 1.f : 0.f;
        }
    }
    __syncthreads();

    float* part = ws + WS_PART + (size_t)blockIdx.x * PART_STRIDE;
    for (int i = t; i < NJ * DIM; i += 1024)
        part[i] = acc[i];
    if (lane < 32)
        part[NJ * DIM + jlo + lane] = cnt;     // disjoint j-ranges per wave
}

// k_red: sum nacc partials -> ESUM + CNT. 8 independent chains in flight.
__global__ void k_red(float* __restrict__ ws, int nacc) {
    int o = blockIdx.x * 256 + threadIdx.x;
    if (o >= PART_STRIDE) return;
    const float* p = ws + WS_PART + o;
    float s0 = 0.f, s1 = 0.f, s2 = 0.f, s3 = 0.f;
    float s4 = 0.f, s5 = 0.f, s6 = 0.f, s7 = 0.f;
    int b = 0;
    for (; b + 8 <= nacc; b += 8) {
        s0 += p[(size_t)(b+0) * PART_STRIDE];
        s1 += p[(size_t)(b+1) * PART_STRIDE];
        s2 += p[(size_t)(b+2) * PART_STRIDE];
        s3 += p[(size_t)(b+3) * PART_STRIDE];
        s4 += p[(size_t)(b+4) * PART_STRIDE];
        s5 += p[(size_t)(b+5) * PART_STRIDE];
        s6 += p[(size_t)(b+6) * PART_STRIDE];
        s7 += p[(size_t)(b+7) * PART_STRIDE];
    }
    for (; b < nacc; ++b) s0 += p[(size_t)b * PART_STRIDE];
    float s = ((s0 + s1) + (s2 + s3)) + ((s4 + s5) + (s6 + s7));
    if (o < NJ * DIM) ws[WS_ESUM + o] = s;
    else              ws[WS_CNT + (o - NJ * DIM)] = s;
}

// fallback (tiny ws): scan-per-code segment sum (correct, slow)
__global__ __launch_bounds__(256) void k_seg(
        const float* __restrict__ x,
        float* __restrict__ ws) {
    __shared__ float wsum[4][DIM];
    __shared__ float wcnt[4];
    const int j = blockIdx.x;
    const int t = threadIdx.x;
    const int lane = t & 63, wid = t >> 6;
    const int* __restrict__ ind = (const int*)ws + WS_IND;

    float acc[DIM];
    #pragma unroll
    for (int d = 0; d < DIM; ++d) acc[d] = 0.f;
    int cnt = 0;

    for (int i = 0; i < NROW / 4 / 256; ++i) {
        int r4 = i * 256 + t;
        int4 iv = *(const int4*)(ind + 4 * r4);
        int rows[4] = {4*r4, 4*r4+1, 4*r4+2, 4*r4+3};
        int js[4] = {iv.x, iv.y, iv.z, iv.w};
        #pragma unroll
        for (int k = 0; k < 4; ++k) {
            if (js[k] == j) {
                const float4* xr = (const float4*)(x + (size_t)rows[k] * DIM);
                #pragma unroll
                for (int q = 0; q < 16; ++q) {
                    float4 v = xr[q];
                    acc[4*q+0] += v.x; acc[4*q+1] += v.y;
                    acc[4*q+2] += v.z; acc[4*q+3] += v.w;
                }
                cnt++;
            }
        }
    }
    #pragma unroll
    for (int d = 0; d < DIM; ++d) {
        float v = acc[d];
        #pragma unroll
        for (int off = 1; off < 64; off <<= 1) v += __shfl_xor(v, off);
        if (lane == 0) wsum[wid][d] = v;
    }
    {
        float c = (float)cnt;
        #pragma unroll
        for (int off = 1; off < 64; off <<= 1) c += __shfl_xor(c, off);
        if (lane == 0) wcnt[wid] = c;
    }
    __syncthreads();
    if (t < DIM) {
        float s = wsum[0][t] + wsum[1][t] + wsum[2][t] + wsum[3][t];
        ws[WS_ESUM + (size_t)j * DIM + t] = s;
        if (t == 0) ws[WS_CNT + j] = wcnt[0] + wcnt[1] + wcnt[2] + wcnt[3];
    }
}

// k2a: new_cluster_size, n, total diff (NBLK1=1024 diff partials -> float2)
__global__ void k2a(const float* __restrict__ cluster_size,
                    float* __restrict__ ws, float* __restrict__ out) {
    __shared__ float part[8];
    __shared__ float dpart[8];
    int j = threadIdx.x;  // 512 threads
    float ncs = cluster_size[j] * DECAY + ONE_MINUS_DECAY * ws[WS_CNT + j];
    out[OFF_NCS + j] = ncs;
    float2 dp = *(const float2*)(ws + WS_DIFFP + 2 * j);
    float dv = dp.x + dp.y;
    float v = ncs;
    #pragma unroll
    for (int off = 1; off < 64; off <<= 1) {
        v  += __shfl_xor(v, off);
        dv += __shfl_xor(dv, off);
    }
    if ((j & 63) == 0) { part[j >> 6] = v; dpart[j >> 6] = dv; }
    __syncthreads();
    if (j == 0) {
        float n = 0.f, dt = 0.f;
        #pragma unroll
        for (int w = 0; w < 8; ++w) { n += part[w]; dt += dpart[w]; }
        ws[WS_N] = n;
        ws[WS_DIFF] = dt;
    }
}

// k2b: new_embed_avg, new_embed, diff
__global__ void k2b(const float* __restrict__ embed_avg,
                    const float* __restrict__ ws,
                    float* __restrict__ out) {
    int i4 = blockIdx.x * 256 + threadIdx.x;  // 0..8191
    int base = i4 * 4;
    int d  = base >> 9;
    int j0 = base & 511;
    float n = ws[WS_N];
    float denom = n + (float)NJ * EPS;
    float4 avg = *(const float4*)(embed_avg + base);
    float a[4] = {avg.x, avg.y, avg.z, avg.w};
    float4 nea, ne;
    float* pa = &nea.x;
    float* pe = &ne.x;
    #pragma unroll
    for (int k = 0; k < 4; ++k) {
        int j = j0 + k;
        float es  = ws[WS_ESUM + (size_t)j * DIM + d];
        float na  = a[k] * DECAY + ONE_MINUS_DECAY * es;
        float ncs = out[OFF_NCS + j];
        float cs  = (ncs + EPS) / denom * n;
        pa[k] = na;
        pe[k] = na / cs;
    }
    *(float4*)(out + OFF_NEA + base) = nea;
    *(float4*)(out + OFF_NE  + base) = ne;
    if (i4 == 0) out[OFF_DIFF] = ws[WS_DIFF] * (1.0f / 8388608.0f);
}

extern "C" void kernel_launch(void* const* d_in, const int* in_sizes, int n_in,
                              void* d_out, int out_size, void* d_ws, size_t ws_size,
                              hipStream_t stream) {
    const float* x            = (const float*)d_in[0];
    const float* embed        = (const float*)d_in[1];
    const float* cluster_size = (const float*)d_in[2];
    const float* embed_avg    = (const float*)d_in[3];
    float* out = (float*)d_out;
    float* ws  = (float*)d_ws;

    // pick nacc (power of 2, <=256 -> all CUs) so partials fit in ws
    size_t ws_floats = ws_size / 4;
    size_t avail = ws_floats > WS_PART ? ws_floats - WS_PART : 0;
    int nacc = 256;
    while (nacc > 1 && (size_t)nacc * PART_STRIDE > avail) nacc >>= 1;
    bool use_acc = (size_t)nacc * PART_STRIDE <= avail;

    k0_prep<<<2, 256, 0, stream>>>(embed, ws);
    k1_main<<<NBLK1, 256, 0, stream>>>(x, embed, ws, out);
    if (use_acc) {
        k_acc<<<nacc, 1024, 0, stream>>>(x, ws, NROW / nacc);
        k_red<<<(PART_STRIDE + 255) / 256, 256, 0, stream>>>(ws, nacc);
    } else {
        k_seg<<<NJ, 256, 0, stream>>>(x, ws);
    }
    k2a<<<1, 512, 0, stream>>>(cluster_size, ws, out);
    k2b<<<32, 256, 0, stream>>>(embed_avg, ws, out);
}

// Round 12
// 185.322 us; speedup vs baseline: 4.3602x; 1.3490x over previous
//
#include <hip/hip_runtime.h>

#define DECAY 0.99f
#define ONE_MINUS_DECAY 0.01f
#define EPS 1e-5f

#define NROW 131072
#define DIM 64
#define NJ 512
#define RBM 64                 // rows per block (k1)
#define NBLK1 (NROW / RBM)     // 2048

// d_out offsets (floats), in reference return order
#define OFF_Q    0          // quantize_st: 8388608
#define OFF_DIFF 8388608    // diff scalar
#define OFF_IND  8388609    // embed_ind: 131072
#define OFF_NE   8519681    // new_embed: 64*512
#define OFF_NCS  8552449    // new_cluster_size: 512
#define OFF_NEA  8552961    // new_embed_avg: 64*512

// ws offsets (floats)
#define WS_QNORM 0          // 512
#define WS_EMBT  512        // embed^T: 512*64
#define WS_ESUM  33280      // embed_sum^T: 512*64 (code-major)
#define WS_CNT   66048      // 512
#define WS_DIFF  66560      // 1
#define WS_N     66561      // 1
#define WS_DIFFP 66564      // 2048 per-block diff partials
#define WS_IND   68612      // 131072 ints
#define WS_EPACK 199684     // 65536 shorts = 32768 floats: packed bf16 h/l B-frags
#define WS_PART  232452     // nacc * 33280 partials
#define PART_STRIDE 33280

typedef __attribute__((ext_vector_type(8))) short bf16x8;
typedef __attribute__((ext_vector_type(4))) float f32x4;

__device__ inline unsigned short bf16rn(float f) {          // round-to-nearest bf16
    unsigned u = __float_as_uint(f);
    return (unsigned short)((u + 0x7FFFu + ((u >> 16) & 1u)) >> 16);
}
__device__ inline float bf16tof(unsigned short h) {
    return __uint_as_float(((unsigned)h) << 16);
}

// k0: qn + embed^T + packed bf16-split B-fragments.
// Packed layout (shorts): [ct 0..31][s 0..1][plane h/l][lane 0..63][8] where
// value = e[k = s*32 + (lane>>4)*8 + i][col = ct*16 + (lane&15)] — exactly the
// mfma_f32_16x16x32_bf16 B-fragment per-lane order (col=lane&15, 8 consecutive k).
__global__ void k0_prep(const float* __restrict__ embed, float* __restrict__ ws) {
    int tid = blockIdx.x * 256 + threadIdx.x;    // grid 16x256 = 4096
    {
        int ct = tid >> 7, s = (tid >> 6) & 1, l = tid & 63;
        int col = ct * 16 + (l & 15);
        int k0  = s * 32 + (l >> 4) * 8;
        short* ep = (short*)(ws + WS_EPACK);
        int baseh = (((ct * 2 + s) * 2 + 0) * 64 + l) * 8;
        int basel = (((ct * 2 + s) * 2 + 1) * 64 + l) * 8;
        #pragma unroll
        for (int i = 0; i < 8; ++i) {
            float v = embed[(size_t)(k0 + i) * NJ + col];
            unsigned short h = bf16rn(v);
            ep[baseh + i] = (short)h;
            ep[basel + i] = (short)bf16rn(v - bf16tof(h));
        }
    }
    if (tid < NJ) {
        int j = tid;
        float q = 0.f;
        #pragma unroll
        for (int d = 0; d < DIM; ++d) {
            float v = embed[d * NJ + j];
            q += v * v;
            ws[WS_EMBT + j * DIM + d] = v;
        }
        ws[WS_QNORM + j] = q;
    }
}

// k1: MFMA distance matmul. 2048 blocks x 4 waves; wave owns 16 rows x 512 cols.
// x split in-register to bf16 (xh,xl); S = xh*eh + xl*eh + xh*el + xl*el (4-term,
// fp32-accurate to ~1e-6 rel). d = ||x||^2 - 2S + ||e||^2 in fp32, running argmin.
// C layout (m89-verified): col=lane&15, row=(lane>>4)*4+reg.
__global__ __launch_bounds__(256) void k1_main(
        const float* __restrict__ x,
        const float* __restrict__ embed,
        float* __restrict__ ws,
        float* __restrict__ out) {
    __shared__ short Bsm[16384];   // 32 KB: one 128-col group, h/l planes
    __shared__ float qn_s[NJ];
    __shared__ float xn_s[RBM];
    __shared__ float bval[RBM];
    __shared__ int   bidx[RBM];

    const int t = threadIdx.x;
    const int lane = t & 63, w = t >> 6;
    const int row0 = blockIdx.x * RBM;

    if (t < 128) *(float4*)&qn_s[4 * t] = *(const float4*)(ws + WS_QNORM + 4 * t);
    if (t < RBM) {
        const float* xr = x + (size_t)(row0 + t) * DIM;
        float s = 0.f;
        #pragma unroll
        for (int q = 0; q < 16; ++q) {
            float4 v = *(const float4*)(xr + 4 * q);
            s += v.x*v.x + v.y*v.y + v.z*v.z + v.w*v.w;
        }
        xn_s[t] = s;
    }

    // A-fragments: row = 16w + (lane&15), k = s*32 + (lane>>4)*8 .. +7
    bf16x8 ah0, ah1, al0, al1;
    {
        const float* xr = x + (size_t)(row0 + 16 * w + (lane & 15)) * DIM + (lane >> 4) * 8;
        #pragma unroll
        for (int s = 0; s < 2; ++s) {
            float4 f0 = *(const float4*)(xr + s * 32);
            float4 f1 = *(const float4*)(xr + s * 32 + 4);
            float vv[8] = {f0.x,f0.y,f0.z,f0.w,f1.x,f1.y,f1.z,f1.w};
            bf16x8 h, l;
            #pragma unroll
            for (int i = 0; i < 8; ++i) {
                unsigned short hb = bf16rn(vv[i]);
                h[i] = (short)hb;
                l[i] = (short)bf16rn(vv[i] - bf16tof(hb));
            }
            if (s == 0) { ah0 = h; al0 = l; } else { ah1 = h; al1 = l; }
        }
    }
    __syncthreads();
    const float4 xn4 = *(float4*)&xn_s[16 * w + (lane >> 4) * 4];

    float best0 = 3.4e38f, best1 = 3.4e38f, best2 = 3.4e38f, best3 = 3.4e38f;
    int   bi0 = 0, bi1 = 0, bi2 = 0, bi3 = 0;
    const short* ep = (const short*)(ws + WS_EPACK);

#define MFMA(A,B,C) __builtin_amdgcn_mfma_f32_16x16x32_bf16((A),(B),(C),0,0,0)
#define TILE_EPI(U, ACC) { \
        int col = g * 128 + (U) * 16 + (lane & 15); \
        float qv = qn_s[col]; \
        float dd; \
        dd = xn4.x - 2.f*(ACC)[0] + qv; if (dd < best0) { best0 = dd; bi0 = col; } \
        dd = xn4.y - 2.f*(ACC)[1] + qv; if (dd < best1) { best1 = dd; bi1 = col; } \
        dd = xn4.z - 2.f*(ACC)[2] + qv; if (dd < best2) { best2 = dd; bi2 = col; } \
        dd = xn4.w - 2.f*(ACC)[3] + qv; if (dd < best3) { best3 = dd; bi3 = col; } }

    for (int g = 0; g < 4; ++g) {
        __syncthreads();   // previous group's reads complete
        {
            const int4* src = (const int4*)(ep + g * 16384);
            int4* dst = (int4*)Bsm;
            #pragma unroll
            for (int i = 0; i < 8; ++i) dst[t + 256 * i] = src[t + 256 * i];
        }
        __syncthreads();

        #pragma unroll
        for (int ct2 = 0; ct2 < 4; ++ct2) {
            const int u0 = ct2 * 2, u1 = u0 + 1;
            bf16x8 b0h0 = *(bf16x8*)&Bsm[((u0*2+0)*2+0)*512 + lane*8];
            bf16x8 b0l0 = *(bf16x8*)&Bsm[((u0*2+0)*2+1)*512 + lane*8];
            bf16x8 b0h1 = *(bf16x8*)&Bsm[((u0*2+1)*2+0)*512 + lane*8];
            bf16x8 b0l1 = *(bf16x8*)&Bsm[((u0*2+1)*2+1)*512 + lane*8];
            bf16x8 b1h0 = *(bf16x8*)&Bsm[((u1*2+0)*2+0)*512 + lane*8];
            bf16x8 b1l0 = *(bf16x8*)&Bsm[((u1*2+0)*2+1)*512 + lane*8];
            bf16x8 b1h1 = *(bf16x8*)&Bsm[((u1*2+1)*2+0)*512 + lane*8];
            bf16x8 b1l1 = *(bf16x8*)&Bsm[((u1*2+1)*2+1)*512 + lane*8];
            f32x4 acc0 = {0.f, 0.f, 0.f, 0.f};
            f32x4 acc1 = {0.f, 0.f, 0.f, 0.f};
            acc0 = MFMA(ah0, b0h0, acc0);  acc1 = MFMA(ah0, b1h0, acc1);
            acc0 = MFMA(ah1, b0h1, acc0);  acc1 = MFMA(ah1, b1h1, acc1);
            acc0 = MFMA(al0, b0h0, acc0);  acc1 = MFMA(al0, b1h0, acc1);
            acc0 = MFMA(al1, b0h1, acc0);  acc1 = MFMA(al1, b1h1, acc1);
            acc0 = MFMA(ah0, b0l0, acc0);  acc1 = MFMA(ah0, b1l0, acc1);
            acc0 = MFMA(ah1, b0l1, acc0);  acc1 = MFMA(ah1, b1l1, acc1);
            acc0 = MFMA(al0, b0l0, acc0);  acc1 = MFMA(al0, b1l0, acc1);
            acc0 = MFMA(al1, b0l1, acc0);  acc1 = MFMA(al1, b1l1, acc1);
            TILE_EPI(u0, acc0);
            TILE_EPI(u1, acc1);
        }
    }
#undef MFMA
#undef TILE_EPI

    // argmin across the 16 col-lanes sharing each row (lowest index on ties)
    #pragma unroll
    for (int off = 1; off < 16; off <<= 1) {
        float ov; int oi;
        ov = __shfl_xor(best0, off); oi = __shfl_xor(bi0, off);
        if (ov < best0 || (ov == best0 && oi < bi0)) { best0 = ov; bi0 = oi; }
        ov = __shfl_xor(best1, off); oi = __shfl_xor(bi1, off);
        if (ov < best1 || (ov == best1 && oi < bi1)) { best1 = ov; bi1 = oi; }
        ov = __shfl_xor(best2, off); oi = __shfl_xor(bi2, off);
        if (ov < best2 || (ov == best2 && oi < bi2)) { best2 = ov; bi2 = oi; }
        ov = __shfl_xor(best3, off); oi = __shfl_xor(bi3, off);
        if (ov < best3 || (ov == best3 && oi < bi3)) { best3 = ov; bi3 = oi; }
    }
    if ((lane & 15) == 0) {
        int rl = 16 * w + (lane >> 4) * 4;
        bval[rl + 0] = best0; bidx[rl + 0] = bi0;
        bval[rl + 1] = best1; bidx[rl + 1] = bi1;
        bval[rl + 2] = best2; bidx[rl + 2] = bi2;
        bval[rl + 3] = best3; bidx[rl + 3] = bi3;
    }
    __syncthreads();

    // quantize write (x + (q - x) matches reference rounding); x re-read (L3-warm)
    {
        int r = t >> 2, c = t & 3;
        int bi = bidx[r];
        const float* eT = ws + WS_EMBT + (size_t)bi * DIM;
        const float* xr = x + (size_t)(row0 + r) * DIM;
        #pragma unroll
        for (int k = 0; k < 4; ++k) {
            int c4 = c + 4 * k;
            float4 q = *(const float4*)(eT + 4 * c4);
            float4 xv = *(const float4*)(xr + 4 * c4);
            float4 o;
            o.x = xv.x + (q.x - xv.x);
            o.y = xv.y + (q.y - xv.y);
            o.z = xv.z + (q.z - xv.z);
            o.w = xv.w + (q.w - xv.w);
            *(float4*)(out + OFF_Q + (size_t)(row0 + r) * DIM + 4 * c4) = o;
        }
    }
    if (t < RBM) {
        int bi = bidx[t];
        out[OFF_IND + row0 + t] = (float)bi;
        ((int*)ws)[WS_IND + row0 + t] = bi;
        float v = bval[t];
        #pragma unroll
        for (int off = 1; off < 64; off <<= 1) v += __shfl_xor(v, off);
        if (t == 0) ws[WS_DIFFP + blockIdx.x] = v;
    }
}

// k_acc: wave-owned j-range histogram — NO atomics, race-free by partition.
__global__ __launch_bounds__(1024) void k_acc(
        const float* __restrict__ x,
        float* __restrict__ ws,
        int rows_per_blk) {
    __shared__ float acc[NJ * DIM];   // [j][d], 128 KB
    const int t = threadIdx.x;
    const int lane = t & 63, wid = t >> 6;
    for (int i = t; i < NJ * DIM; i += 1024) acc[i] = 0.f;
    __syncthreads();

    const int* __restrict__ ind = (const int*)ws + WS_IND;
    const int row0 = blockIdx.x * rows_per_blk;
    const int jlo = wid * 32, jhi = jlo + 32;

    float cnt = 0.f;

    for (int base = 0; base < rows_per_blk; base += 64) {
        int j64 = ind[row0 + base + lane];
        unsigned long long owned = __ballot(j64 >= jlo && j64 < jhi);
        while (owned) {
            int r2 = __ffsll(owned) - 1;
            owned &= owned - 1;
            int j = __shfl(j64, r2);
            float v = x[(size_t)(row0 + base + r2) * DIM + lane];
            acc[j * DIM + lane] += v;
            cnt += (lane == (j & 31)) ? 1.f : 0.f;
        }
    }
    __syncthreads();

    float* part = ws + WS_PART + (size_t)blockIdx.x * PART_STRIDE;
    for (int i = t; i < NJ * DIM; i += 1024)
        part[i] = acc[i];
    if (lane < 32)
        part[NJ * DIM + jlo + lane] = cnt;
}

// k_red: sum nacc partials -> ESUM + CNT. 8 chains in flight.
__global__ void k_red(float* __restrict__ ws, int nacc) {
    int o = blockIdx.x * 256 + threadIdx.x;
    if (o >= PART_STRIDE) return;
    const float* p = ws + WS_PART + o;
    float s0 = 0.f, s1 = 0.f, s2 = 0.f, s3 = 0.f;
    float s4 = 0.f, s5 = 0.f, s6 = 0.f, s7 = 0.f;
    int b = 0;
    for (; b + 8 <= nacc; b += 8) {
        s0 += p[(size_t)(b+0) * PART_STRIDE];
        s1 += p[(size_t)(b+1) * PART_STRIDE];
        s2 += p[(size_t)(b+2) * PART_STRIDE];
        s3 += p[(size_t)(b+3) * PART_STRIDE];
        s4 += p[(size_t)(b+4) * PART_STRIDE];
        s5 += p[(size_t)(b+5) * PART_STRIDE];
        s6 += p[(size_t)(b+6) * PART_STRIDE];
        s7 += p[(size_t)(b+7) * PART_STRIDE];
    }
    for (; b < nacc; ++b) s0 += p[(size_t)b * PART_STRIDE];
    float s = ((s0 + s1) + (s2 + s3)) + ((s4 + s5) + (s6 + s7));
    if (o < NJ * DIM) ws[WS_ESUM + o] = s;
    else              ws[WS_CNT + (o - NJ * DIM)] = s;
}

// fallback (tiny ws): scan-per-code segment sum (correct, slow)
__global__ __launch_bounds__(256) void k_seg(
        const float* __restrict__ x,
        float* __restrict__ ws) {
    __shared__ float wsum[4][DIM];
    __shared__ float wcnt[4];
    const int j = blockIdx.x;
    const int t = threadIdx.x;
    const int lane = t & 63, wid = t >> 6;
    const int* __restrict__ ind = (const int*)ws + WS_IND;

    float acc[DIM];
    #pragma unroll
    for (int d = 0; d < DIM; ++d) acc[d] = 0.f;
    int cnt = 0;

    for (int i = 0; i < NROW / 4 / 256; ++i) {
        int r4 = i * 256 + t;
        int4 iv = *(const int4*)(ind + 4 * r4);
        int rows[4] = {4*r4, 4*r4+1, 4*r4+2, 4*r4+3};
        int js[4] = {iv.x, iv.y, iv.z, iv.w};
        #pragma unroll
        for (int k = 0; k < 4; ++k) {
            if (js[k] == j) {
                const float4* xr = (const float4*)(x + (size_t)rows[k] * DIM);
                #pragma unroll
                for (int q = 0; q < 16; ++q) {
                    float4 v = xr[q];
                    acc[4*q+0] += v.x; acc[4*q+1] += v.y;
                    acc[4*q+2] += v.z; acc[4*q+3] += v.w;
                }
                cnt++;
            }
        }
    }
    #pragma unroll
    for (int d = 0; d < DIM; ++d) {
        float v = acc[d];
        #pragma unroll
        for (int off = 1; off < 64; off <<= 1) v += __shfl_xor(v, off);
        if (lane == 0) wsum[wid][d] = v;
    }
    {
        float c = (float)cnt;
        #pragma unroll
        for (int off = 1; off < 64; off <<= 1) c += __shfl_xor(c, off);
        if (lane == 0) wcnt[wid] = c;
    }
    __syncthreads();
    if (t < DIM) {
        float s = wsum[0][t] + wsum[1][t] + wsum[2][t] + wsum[3][t];
        ws[WS_ESUM + (size_t)j * DIM + t] = s;
        if (t == 0) ws[WS_CNT + j] = wcnt[0] + wcnt[1] + wcnt[2] + wcnt[3];
    }
}

// k2a: new_cluster_size, n, total diff (2048 diff partials -> float4)
__global__ void k2a(const float* __restrict__ cluster_size,
                    float* __restrict__ ws, float* __restrict__ out) {
    __shared__ float part[8];
    __shared__ float dpart[8];
    int j = threadIdx.x;  // 512 threads
    float ncs = cluster_size[j] * DECAY + ONE_MINUS_DECAY * ws[WS_CNT + j];
    out[OFF_NCS + j] = ncs;
    float4 dp = *(const float4*)(ws + WS_DIFFP + 4 * j);
    float dv = dp.x + dp.y + dp.z + dp.w;
    float v = ncs;
    #pragma unroll
    for (int off = 1; off < 64; off <<= 1) {
        v  += __shfl_xor(v, off);
        dv += __shfl_xor(dv, off);
    }
    if ((j & 63) == 0) { part[j >> 6] = v; dpart[j >> 6] = dv; }
    __syncthreads();
    if (j == 0) {
        float n = 0.f, dt = 0.f;
        #pragma unroll
        for (int w = 0; w < 8; ++w) { n += part[w]; dt += dpart[w]; }
        ws[WS_N] = n;
        ws[WS_DIFF] = dt;
    }
}

// k2b: new_embed_avg, new_embed, diff
__global__ void k2b(const float* __restrict__ embed_avg,
                    const float* __restrict__ ws,
                    float* __restrict__ out) {
    int i4 = blockIdx.x * 256 + threadIdx.x;  // 0..8191
    int base = i4 * 4;
    int d  = base >> 9;
    int j0 = base & 511;
    float n = ws[WS_N];
    float denom = n + (float)NJ * EPS;
    float4 avg = *(const float4*)(embed_avg + base);
    float a[4] = {avg.x, avg.y, avg.z, avg.w};
    float4 nea, ne;
    float* pa = &nea.x;
    float* pe = &ne.x;
    #pragma unroll
    for (int k = 0; k < 4; ++k) {
        int j = j0 + k;
        float es  = ws[WS_ESUM + (size_t)j * DIM + d];
        float na  = a[k] * DECAY + ONE_MINUS_DECAY * es;
        float ncs = out[OFF_NCS + j];
        float cs  = (ncs + EPS) / denom * n;
        pa[k] = na;
        pe[k] = na / cs;
    }
    *(float4*)(out + OFF_NEA + base) = nea;
    *(float4*)(out + OFF_NE  + base) = ne;
    if (i4 == 0) out[OFF_DIFF] = ws[WS_DIFF] * (1.0f / 8388608.0f);
}

extern "C" void kernel_launch(void* const* d_in, const int* in_sizes, int n_in,
                              void* d_out, int out_size, void* d_ws, size_t ws_size,
                              hipStream_t stream) {
    const float* x            = (const float*)d_in[0];
    const float* embed        = (const float*)d_in[1];
    const float* cluster_size = (const float*)d_in[2];
    const float* embed_avg    = (const float*)d_in[3];
    float* out = (float*)d_out;
    float* ws  = (float*)d_ws;

    size_t ws_floats = ws_size / 4;
    size_t avail = ws_floats > WS_PART ? ws_floats - WS_PART : 0;
    int nacc = 256;
    while (nacc > 1 && (size_t)nacc * PART_STRIDE > avail) nacc >>= 1;
    bool use_acc = (size_t)nacc * PART_STRIDE <= avail;

    k0_prep<<<16, 256, 0, stream>>>(embed, ws);
    k1_main<<<NBLK1, 256, 0, stream>>>(x, embed, ws, out);
    if (use_acc) {
        k_acc<<<nacc, 1024, 0, stream>>>(x, ws, NROW / nacc);
        k_red<<<(PART_STRIDE + 255) / 256, 256, 0, stream>>>(ws, nacc);
    } else {
        k_seg<<<NJ, 256, 0, stream>>>(x, ws);
    }
    k2a<<<1, 512, 0, stream>>>(cluster_size, ws, out);
    k2b<<<32, 256, 0, stream>>>(embed_avg, ws, out);
}